// Round 7
// baseline (1359.142 us; speedup 1.0000x reference)
//
#include <hip/hip_runtime.h>
#include <math.h>

#define NBATCH 8
#define NPTS 4096
#define NPOINT 1024
#define NSAMPLE 32
#define PTDIM 67        // 3 xyz + 64 feat
#define BIGF 1e10f
#define NCONS 128       // consumers; grid = 8+64+128 = 200 <= 256 CUs @ 1 blk/CU
#define SPIN_CAP 4096   // x s_sleep(64) ~= 7 ms; legit max wait ~650 us

// DPP ctrl encodings (gfx9/CDNA)
#define DPP_QUAD_XOR1 0xB1   // quad_perm [1,0,3,2]
#define DPP_QUAD_XOR2 0x4E   // quad_perm [2,3,0,1]
#define DPP_ROW_HALF_MIRROR 0x141
#define DPP_ROW_MIRROR 0x140
#define DPP_ROW_BCAST15 0x142
#define DPP_ROW_BCAST31 0x143

template <int CTRL>
__device__ inline float dpp_mov_f(float v) {
  int i = __float_as_int(v);
  return __int_as_float(__builtin_amdgcn_update_dpp(i, i, CTRL, 0xf, 0xf, false));
}
template <int CTRL>
__device__ inline unsigned dpp_mov_u(unsigned v) {
  return (unsigned)__builtin_amdgcn_update_dpp((int)v, (int)v, CTRL, 0xf, 0xf, false);
}
template <int CTRL>
__device__ inline void dpp_min2(unsigned& hi, unsigned& lo) {
  unsigned nh = dpp_mov_u<CTRL>(hi);
  unsigned nl = dpp_mov_u<CTRL>(lo);
  bool take = (nh < hi) || (nh == hi && nl < lo);
  hi = take ? nh : hi;
  lo = take ? nl : lo;
}
__device__ inline unsigned fmap(float d) {
  unsigned b = __float_as_uint(d);
  return ((int)b < 0) ? ~b : (b | 0x80000000u);
}
#define FMAP_INF 0xFF800000u   // fmap(+INF)

// 32-lane-group reductions: 4 VALU-DPP levels + ONE shfl (xor16) per value.
__device__ inline float red32_max(float v) {
  v = fmaxf(v, dpp_mov_f<DPP_QUAD_XOR1>(v));
  v = fmaxf(v, dpp_mov_f<DPP_QUAD_XOR2>(v));
  v = fmaxf(v, dpp_mov_f<DPP_ROW_HALF_MIRROR>(v));
  v = fmaxf(v, dpp_mov_f<DPP_ROW_MIRROR>(v));
  v = fmaxf(v, __shfl_xor(v, 16));
  return v;
}
__device__ inline float red32_sum(float v) {
  v += dpp_mov_f<DPP_QUAD_XOR1>(v);
  v += dpp_mov_f<DPP_QUAD_XOR2>(v);
  v += dpp_mov_f<DPP_ROW_HALF_MIRROR>(v);
  v += dpp_mov_f<DPP_ROW_MIRROR>(v);
  v += __shfl_xor(v, 16);
  return v;
}

// ---------------------------------------------------------------------------
// LDS unions. ProjS is round-0 (135.7 KB): DELIBERATELY large -> 1 block/CU
// for the whole kernel (2x135.7 > 160 KB). Grid 200 <= 256 CUs -> every
// block owns its CU: (a) all co-resident regardless of dispatch order ->
// polling can't deadlock; (b) FPS's serial chain never shares SIMD issue
// with consumer waves (round 6's 2-blk/CU co-residency cost FPS ~50%).
// ---------------------------------------------------------------------------
struct FpsS {
  unsigned long long slots[2][4];
  float4 C[NPTS];                                  // 64 KB
};
struct ProjS {                                     // round-0 layout, 135.7 KB
  float As[131 * 128];
  float w0[64 * 64], w1[64 * 64], w2[128 * 64];
  float bb0[64], ss0[64], ee0[64];
  float bb1[64], ss1[64], ee1[64];
  float bb2[128], ss2[128], ee2[128];
};
struct ConsS {                                     // ~17 KB
  float dbuf[4][512];
  int   ibuf[4][512];
  int   gidxS[4][32];
  int   cIS[4];
  float pcS[128];
};
#define SMX1 (sizeof(ProjS) > sizeof(FpsS) ? sizeof(ProjS) : sizeof(FpsS))
#define F1_SMEM (SMX1 > sizeof(ConsS) ? SMX1 : sizeof(ConsS))

// ---------------------------------------------------------------------------
// FPS: round-0 structure VERBATIM (4 waves, 16 pts/lane, float4 C in LDS,
// split-phase DPP argmax — measured best at 650 us). Only changes:
// (a) all-threads __threadfence after X/Y/Z+C init; (b) tid0 publishes
// cidx[t] per iteration via RELAXED agent atomic store (fire-and-forget).
// ---------------------------------------------------------------------------
__device__ void fps_body(char* smemRaw, const float* __restrict__ pts,
                         int* __restrict__ cidx, float* __restrict__ X,
                         float* __restrict__ Y, float* __restrict__ Z) {
#pragma clang fp contract(off)
  FpsS* S = (FpsS*)smemRaw;
  const int b = blockIdx.x, tid = threadIdx.x;
  const int w = tid >> 6, lane = tid & 63;
  const float* pb = pts + (size_t)b * NPTS * PTDIM;
  float2 px2[8], py2[8], pz2[8];
  float dl[16];
  #pragma unroll
  for (int k = 0; k < 16; k++) {
    int j = tid + (k << 8);
    const float* pj = pb + (size_t)j * PTDIM;
    float x = pj[0], y = pj[1], z = pj[2];
    if (k & 1) { px2[k >> 1].y = x; py2[k >> 1].y = y; pz2[k >> 1].y = z; }
    else       { px2[k >> 1].x = x; py2[k >> 1].x = y; pz2[k >> 1].x = z; }
    S->C[j] = make_float4(x, y, z, 0.0f);
    X[b * NPTS + j] = x; Y[b * NPTS + j] = y; Z[b * NPTS + j] = z;  // SoA out
    dl[k] = BIGF;
  }
  __threadfence();        // every thread flushes its X/Y/Z before any publish
  __syncthreads();
  int f = 0;
  float4 c0 = S->C[0];
  float cx = c0.x, cy = c0.y, cz = c0.z;
  for (int t = 0; t < NPOINT; t++) {
    if (tid == 0)
      __hip_atomic_store(&cidx[b * NPOINT + t], f, __ATOMIC_RELAXED,
                         __HIP_MEMORY_SCOPE_AGENT);   // publish BEFORE update
    float2 c2x = make_float2(cx, cx);
    float2 c2y = make_float2(cy, cy);
    float2 c2z = make_float2(cz, cz);
    #pragma unroll
    for (int m = 0; m < 8; m++) {
      float2 dx = px2[m] - c2x;
      float2 dy = py2[m] - c2y;
      float2 dz = pz2[m] - c2z;
      float2 d = (dx * dx + dy * dy) + dz * dz;    // pk ops, contract OFF
      dl[2 * m]     = fminf(dl[2 * m],     d.x);
      dl[2 * m + 1] = fminf(dl[2 * m + 1], d.y);
    }
    float u0 = fmaxf(dl[0], dl[1]),  u1 = fmaxf(dl[2], dl[3]);
    float u2 = fmaxf(dl[4], dl[5]),  u3 = fmaxf(dl[6], dl[7]);
    float u4 = fmaxf(dl[8], dl[9]),  u5 = fmaxf(dl[10], dl[11]);
    float u6 = fmaxf(dl[12], dl[13]), u7 = fmaxf(dl[14], dl[15]);
    float v0 = fmaxf(u0, u1), v1 = fmaxf(u2, u3);
    float v2 = fmaxf(u4, u5), v3 = fmaxf(u6, u7);
    float bv = fmaxf(fmaxf(v0, v1), fmaxf(v2, v3));
    float m = bv;
    m = fmaxf(m, dpp_mov_f<DPP_QUAD_XOR1>(m));
    m = fmaxf(m, dpp_mov_f<DPP_QUAD_XOR2>(m));
    m = fmaxf(m, dpp_mov_f<DPP_ROW_HALF_MIRROR>(m));
    m = fmaxf(m, dpp_mov_f<DPP_ROW_MIRROR>(m));
    m = fmaxf(m, dpp_mov_f<DPP_ROW_BCAST15>(m));
    m = fmaxf(m, dpp_mov_f<DPP_ROW_BCAST31>(m));   // lane63 = wave max
    unsigned wmaxbits = (unsigned)__builtin_amdgcn_readlane(__float_as_int(m), 63);
    // min index among holders (bit-equality exact: no -0 from sums of squares)
    unsigned c_[16];
    #pragma unroll
    for (int k = 0; k < 16; k++)
      c_[k] = (__float_as_uint(dl[k]) == wmaxbits) ? (unsigned)(tid + (k << 8)) : 0xFFFFFFFFu;
    unsigned q0 = min(c_[0], c_[1]),  q1 = min(c_[2], c_[3]);
    unsigned q2 = min(c_[4], c_[5]),  q3 = min(c_[6], c_[7]);
    unsigned q4 = min(c_[8], c_[9]),  q5 = min(c_[10], c_[11]);
    unsigned q6 = min(c_[12], c_[13]), q7 = min(c_[14], c_[15]);
    unsigned r0 = min(q0, q1), r1 = min(q2, q3), r2 = min(q4, q5), r3 = min(q6, q7);
    unsigned cand = min(min(r0, r1), min(r2, r3));
    cand = min(cand, dpp_mov_u<DPP_QUAD_XOR1>(cand));
    cand = min(cand, dpp_mov_u<DPP_QUAD_XOR2>(cand));
    cand = min(cand, dpp_mov_u<DPP_ROW_HALF_MIRROR>(cand));
    cand = min(cand, dpp_mov_u<DPP_ROW_MIRROR>(cand));
    cand = min(cand, dpp_mov_u<DPP_ROW_BCAST15>(cand));
    cand = min(cand, dpp_mov_u<DPP_ROW_BCAST31>(cand));  // lane63 = min j
    unsigned jmin = (unsigned)__builtin_amdgcn_readlane((int)cand, 63);
    if (lane == 0)
      S->slots[t & 1][w] = ((unsigned long long)wmaxbits << 32) |
                           (unsigned long long)(NPTS - 1 - jmin);
    __syncthreads();
    unsigned long long s0 = S->slots[t & 1][0], s1 = S->slots[t & 1][1];
    unsigned long long s2 = S->slots[t & 1][2], s3 = S->slots[t & 1][3];
    unsigned long long m0 = s0 > s1 ? s0 : s1;
    unsigned long long m1 = s2 > s3 ? s2 : s3;
    unsigned long long best = m0 > m1 ? m0 : m1;
    f = NPTS - 1 - (int)(best & 0xFFFFFFFFull);
    float4 cc = S->C[f];
    cx = cc.x; cy = cc.y; cz = cc.z;
  }
}

// ---------------------------------------------------------------------------
// PROJ-MLP: round-0 body VERBATIM (all weights + A staged in LDS, 2 rows per
// thread, op order bit-identical -> fast and numerically exact). Ends with
// all-threads fence + barrier + release-increment of done[batch].
// ---------------------------------------------------------------------------
__device__ void projmlp_body(char* smemRaw, const float* __restrict__ pts,
    const float* __restrict__ W0, const float* __restrict__ B0, const float* __restrict__ G0, const float* __restrict__ E0,
    const float* __restrict__ W1, const float* __restrict__ B1, const float* __restrict__ G1, const float* __restrict__ E1,
    const float* __restrict__ W2, const float* __restrict__ B2, const float* __restrict__ G2, const float* __restrict__ E2,
    const float* __restrict__ Aatt,
    float* __restrict__ mfeat, float* __restrict__ P, int* __restrict__ done) {
  ProjS* S = (ProjS*)smemRaw;
  const float INVS = 0.99999500003750f;            // 1/sqrt(1+1e-5)
  const int t = threadIdx.x;
  for (int i = t; i < 131 * 128; i += 256) S->As[i] = Aatt[i];
  for (int i = t; i < 4096; i += 256) { S->w0[i] = W0[i]; S->w1[i] = W1[i]; }
  for (int i = t; i < 8192; i += 256) S->w2[i] = W2[i];
  if (t < 64) {
    S->bb0[t] = B0[t]; S->ss0[t] = G0[t] * INVS; S->ee0[t] = E0[t];
    S->bb1[t] = B1[t]; S->ss1[t] = G1[t] * INVS; S->ee1[t] = E1[t];
  }
  if (t < 128) { S->bb2[t] = B2[t]; S->ss2[t] = G2[t] * INVS; S->ee2[t] = E2[t]; }
  __syncthreads();

  const int pb = blockIdx.x - 8;                   // 0..63
  for (int rr = 0; rr < 2; rr++) {
    const size_t r = (size_t)pb * 512 + rr * 256 + t;   // row 0..32767
    const float* xr = pts + r * PTDIM + 3;
    float x[64];
    #pragma unroll
    for (int c = 0; c < 64; c++) x[c] = xr[c];

    float h1[64];
    #pragma unroll
    for (int o = 0; o < 64; o++) {
      float acc = S->bb0[o];
      #pragma unroll
      for (int c = 0; c < 64; c += 4) {
        float4 wv = *(const float4*)&S->w0[o * 64 + c];
        acc = fmaf(wv.x, x[c], acc);
        acc = fmaf(wv.y, x[c + 1], acc);
        acc = fmaf(wv.z, x[c + 2], acc);
        acc = fmaf(wv.w, x[c + 3], acc);
      }
      h1[o] = fmaxf(fmaf(acc, S->ss0[o], S->ee0[o]), 0.0f);
    }
    float h2[64];
    #pragma unroll
    for (int o = 0; o < 64; o++) {
      float acc = S->bb1[o];
      #pragma unroll
      for (int c = 0; c < 64; c += 4) {
        float4 wv = *(const float4*)&S->w1[o * 64 + c];
        acc = fmaf(wv.x, h1[c], acc);
        acc = fmaf(wv.y, h1[c + 1], acc);
        acc = fmaf(wv.z, h1[c + 2], acc);
        acc = fmaf(wv.w, h1[c + 3], acc);
      }
      h2[o] = fmaxf(fmaf(acc, S->ss1[o], S->ee1[o]), 0.0f);
    }
    float h3[128];
    float* orow = mfeat + r * 128;
    #pragma unroll
    for (int o = 0; o < 128; o += 4) {
      float a0 = S->bb2[o], a1 = S->bb2[o + 1], a2 = S->bb2[o + 2], a3 = S->bb2[o + 3];
      #pragma unroll
      for (int c = 0; c < 64; c += 4) {
        float4 wv0 = *(const float4*)&S->w2[(o    ) * 64 + c];
        float4 wv1 = *(const float4*)&S->w2[(o + 1) * 64 + c];
        float4 wv2 = *(const float4*)&S->w2[(o + 2) * 64 + c];
        float4 wv3 = *(const float4*)&S->w2[(o + 3) * 64 + c];
        a0 = fmaf(wv0.x, h2[c], a0); a0 = fmaf(wv0.y, h2[c+1], a0); a0 = fmaf(wv0.z, h2[c+2], a0); a0 = fmaf(wv0.w, h2[c+3], a0);
        a1 = fmaf(wv1.x, h2[c], a1); a1 = fmaf(wv1.y, h2[c+1], a1); a1 = fmaf(wv1.z, h2[c+2], a1); a1 = fmaf(wv1.w, h2[c+3], a1);
        a2 = fmaf(wv2.x, h2[c], a2); a2 = fmaf(wv2.y, h2[c+1], a2); a2 = fmaf(wv2.z, h2[c+2], a2); a2 = fmaf(wv2.w, h2[c+3], a2);
        a3 = fmaf(wv3.x, h2[c], a3); a3 = fmaf(wv3.y, h2[c+1], a3); a3 = fmaf(wv3.z, h2[c+2], a3); a3 = fmaf(wv3.w, h2[c+3], a3);
      }
      float4 ov;
      ov.x = fmaxf(fmaf(a0, S->ss2[o    ], S->ee2[o    ]), 0.0f);
      ov.y = fmaxf(fmaf(a1, S->ss2[o + 1], S->ee2[o + 1]), 0.0f);
      ov.z = fmaxf(fmaf(a2, S->ss2[o + 2], S->ee2[o + 2]), 0.0f);
      ov.w = fmaxf(fmaf(a3, S->ss2[o + 3], S->ee2[o + 3]), 0.0f);
      h3[o] = ov.x; h3[o + 1] = ov.y; h3[o + 2] = ov.z; h3[o + 3] = ov.w;
      *(float4*)(orow + o) = ov;
    }
    // P row = [xyz, h3] @ A   (ascending-c order, identical to round-0)
    const float* pr = pts + r * PTDIM;
    float x0 = pr[0], y0 = pr[1], z0 = pr[2];
    float* prow = P + r * 128;
    for (int grp = 0; grp < 4; grp++) {
      const int g0 = grp * 32;
      float acc[32];
      #pragma unroll
      for (int j = 0; j < 32; j++) {
        float a0 = S->As[0 * 128 + g0 + j];
        float a1 = S->As[1 * 128 + g0 + j];
        float a2 = S->As[2 * 128 + g0 + j];
        acc[j] = fmaf(z0, a2, fmaf(y0, a1, x0 * a0));
      }
      #pragma unroll
      for (int c = 0; c < 128; c++) {
        float s = h3[c];
        const float* arow = &S->As[(3 + c) * 128 + g0];
        #pragma unroll
        for (int j = 0; j < 32; j += 4) {
          float4 a = *(const float4*)&arow[j];
          acc[j]   = fmaf(s, a.x, acc[j]);
          acc[j+1] = fmaf(s, a.y, acc[j+1]);
          acc[j+2] = fmaf(s, a.z, acc[j+2]);
          acc[j+3] = fmaf(s, a.w, acc[j+3]);
        }
      }
      #pragma unroll
      for (int j = 0; j < 32; j += 4)
        *(float4*)(prow + g0 + j) = make_float4(acc[j], acc[j+1], acc[j+2], acc[j+3]);
    }
  }
  __threadfence();         // EVERY thread drains + flushes its mfeat/P stores
  __syncthreads();
  if (t == 0)
    __hip_atomic_fetch_add(&done[pb >> 3], 1, __ATOMIC_RELEASE,
                           __HIP_MEMORY_SCOPE_AGENT);
}

// ---------------------------------------------------------------------------
// Consumer: 128 blocks. Block c -> batch b = c & 7 (72%8==0 so blockIdx ≡ b
// mod 8 -> same XCD as FPS block b under round-robin placement: this XCD's
// L2 holds ONE batch's P+mfeat (4 MB, fits) + X/Y/Z (48 KB) -> gathers and
// ball-query reads are L2 hits — this mapping collapsed FETCH 139->56 MB in
// round 6). Residue r = c>>3 (0..15). Iteration i (0..15): wave w handles
// tpos = r + 16*(4i+w) — monotone in i, matches publication order. Hot path
// relaxed-only; one acquire at i==0 (X/Y/Z) + one done[b] gate (mfeat/P).
// ---------------------------------------------------------------------------
__device__ void consumer_body(char* smemRaw,
    const float* __restrict__ X, const float* __restrict__ Y, const float* __restrict__ Z,
    const float* __restrict__ mfeat, const float* __restrict__ P,
    int* __restrict__ cidx, int* __restrict__ done,
    float* __restrict__ out, int c) {
  ConsS* S = (ConsS*)smemRaw;
  const int t = threadIdx.x;
  const int w = t >> 6, lane = t & 63;
  const int b = c & 7, r = c >> 3;                 // 16 consumers per batch
  const float* Xb = X + b * NPTS;
  const float* Yb = Y + b * NPTS;
  const float* Zb = Z + b * NPTS;
  const float R2 = 0.04f;

  for (int i = 0; i < 16; i++) {
    const int tpos = r + 16 * (4 * i + w);
    const int pc = b * NPOINT + tpos;
    // --- bounded RELAXED wait for FPS to publish this center ---
    int cI = -1;
    for (int spin = 0; spin < SPIN_CAP; ++spin) {
      cI = __hip_atomic_load(&cidx[pc], __ATOMIC_RELAXED,
                             __HIP_MEMORY_SCOPE_AGENT);
      if (cI != -1) break;
      __builtin_amdgcn_s_sleep(64);
    }
    // One-time acquire: makes X/Y/Z (written + fenced before the first
    // publish) visible to this block's subsequent NORMAL cached loads.
    if (i == 0)
      (void)__hip_atomic_load(&cidx[pc], __ATOMIC_ACQUIRE,
                              __HIP_MEMORY_SCOPE_AGENT);
    if (cI < 0) cI = 0;                            // bail-safe (never legit)
    if (lane == 0) S->cIS[w] = cI;
    // --- ball query (exact f2 algorithm, per wave) ---
    const float cx = Xb[cI], cy = Yb[cI], cz = Zb[cI];
    const float sc = __fadd_rn(__fadd_rn(__fmul_rn(cx, cx), __fmul_rn(cy, cy)), __fmul_rn(cz, cz));
    int cnt = 0;                                   // wave-uniform
    for (int rr = 0; rr < 16; rr++) {
      const int base = rr * 256 + lane * 4;
      float4 px4 = *(const float4*)(Xb + base);
      float4 py4 = *(const float4*)(Yb + base);
      float4 pz4 = *(const float4*)(Zb + base);
      #pragma unroll
      for (int e = 0; e < 4; e++) {
        float px = e == 0 ? px4.x : e == 1 ? px4.y : e == 2 ? px4.z : px4.w;
        float py = e == 0 ? py4.x : e == 1 ? py4.y : e == 2 ? py4.z : py4.w;
        float pz = e == 0 ? pz4.x : e == 1 ? pz4.y : e == 2 ? pz4.z : pz4.w;
        float dot = __fadd_rn(__fadd_rn(__fmul_rn(cx, px), __fmul_rn(cy, py)), __fmul_rn(cz, pz));
        float sx  = __fadd_rn(__fadd_rn(__fmul_rn(px, px), __fmul_rn(py, py)), __fmul_rn(pz, pz));
        float d   = __fadd_rn(__fadd_rn(__fmul_rn(-2.0f, dot), sc), sx);
        bool pred = !(d > R2);
        unsigned long long mask = __ballot(pred);
        if (pred) {
          int pos = cnt + (int)__popcll(mask & ((1ull << lane) - 1ull));
          if (pos < 512) { S->dbuf[w][pos] = d; S->ibuf[w][pos] = base + e; }
        }
        cnt += (int)__popcll(mask);
      }
    }
    const int K = cnt < 512 ? cnt : 512;
    unsigned long long kk[8];
    #pragma unroll
    for (int kq = 0; kq < 8; kq++) {
      int pos = lane + 64 * kq;
      if (pos < K)
        kk[kq] = ((unsigned long long)fmap(S->dbuf[w][pos]) << 32) | (unsigned)S->ibuf[w][pos];
      else
        kk[kq] = ((unsigned long long)FMAP_INF << 32) | 0x7fffffffu;
    }
    int first = 0;
    for (int it = 0; it < NSAMPLE; it++) {
      unsigned long long best = kk[0];
      #pragma unroll
      for (int kq = 1; kq < 8; kq++) if (kk[kq] < best) best = kk[kq];
      unsigned hi = (unsigned)(best >> 32), lo = (unsigned)best;
      dpp_min2<DPP_QUAD_XOR1>(hi, lo);
      dpp_min2<DPP_QUAD_XOR2>(hi, lo);
      dpp_min2<DPP_ROW_HALF_MIRROR>(hi, lo);
      dpp_min2<DPP_ROW_MIRROR>(hi, lo);
      dpp_min2<DPP_ROW_BCAST15>(hi, lo);
      dpp_min2<DPP_ROW_BCAST31>(hi, lo);           // lane63 = wave min
      unsigned blo = (unsigned)__builtin_amdgcn_readlane((int)lo, 63);
      #pragma unroll
      for (int kq = 0; kq < 8; kq++)
        if ((unsigned)kk[kq] == blo)
          kk[kq] = (kk[kq] & 0xFFFFFFFFull) | ((unsigned long long)FMAP_INF << 32);
      if (it == 0) first = (int)blo;
      if (lane == 0) S->gidxS[w][it] = (it < K) ? (int)blo : first;
    }
    __syncthreads();                               // gidxS/cIS visible to block
    // --- gate mfeat/P reads on projmlp completion (first iteration only) ---
    if (i == 0) {
      for (int spin = 0; spin < SPIN_CAP; ++spin) {
        if (__hip_atomic_load(&done[b], __ATOMIC_RELAXED,
                              __HIP_MEMORY_SCOPE_AGENT) >= 8) break;
        __builtin_amdgcn_s_sleep(64);
      }
      (void)__hip_atomic_load(&done[b], __ATOMIC_ACQUIRE,
                              __HIP_MEMORY_SCOPE_AGENT);
    }
    // --- attention for the 4 centers of this iteration (exact attn code) ---
    for (int cc = 0; cc < 4; cc++) {
      const int pcc = b * NPOINT + r + 16 * (4 * i + cc);
      const int cIc = S->cIS[cc];
      if (t < 128) S->pcS[t] = P[((size_t)b * NPTS + cIc) * 128 + t];
      __syncthreads();
      const int n = t & 31, q = t >> 5;            // q: 0..7, 16 channels each
      const int g = S->gidxS[cc][n];
      const float* Pg = P + ((size_t)b * NPTS + g) * 128 + q * 16;
      const float* Gf = mfeat + ((size_t)b * NPTS + g) * 128 + q * 16;
      float a[16], gfv[16];
      #pragma unroll
      for (int kq = 0; kq < 4; kq++) {
        float4 vg = *(const float4*)(Pg + 4 * kq);
        float4 vc = *(const float4*)&S->pcS[q * 16 + 4 * kq];   // LDS broadcast
        float4 vf = *(const float4*)(Gf + 4 * kq);
        a[4*kq]   = vg.x - vc.x; a[4*kq+1] = vg.y - vc.y;
        a[4*kq+2] = vg.z - vc.z; a[4*kq+3] = vg.w - vc.w;
        gfv[4*kq] = vf.x; gfv[4*kq+1] = vf.y; gfv[4*kq+2] = vf.z; gfv[4*kq+3] = vf.w;
      }
      #pragma unroll
      for (int j = 0; j < 16; j++) a[j] = a[j] >= 0.0f ? a[j] : 0.2f * a[j];
      float e[16], s[16], num[16];
      #pragma unroll
      for (int j = 0; j < 16; j++) {
        float mx = red32_max(a[j]);
        e[j] = expf(a[j] - mx);
      }
      #pragma unroll
      for (int j = 0; j < 16; j++) s[j] = red32_sum(e[j]);
      #pragma unroll
      for (int j = 0; j < 16; j++) num[j] = red32_sum(e[j] * gfv[j]);
      if (n == 0) {
        float* orow = out + (size_t)pcc * 131;
        #pragma unroll
        for (int j = 0; j < 16; j++) orow[3 + q * 16 + j] = num[j] / s[j];
        if (q == 0) {
          orow[0] = Xb[cIc]; orow[1] = Yb[cIc]; orow[2] = Zb[cIc];
        }
      }
      __syncthreads();                             // pcS/gidxS reuse barrier
    }
  }
}

__global__ __launch_bounds__(256) void mega_kernel(const float* __restrict__ pts,
    const float* __restrict__ W0, const float* __restrict__ B0, const float* __restrict__ G0, const float* __restrict__ E0,
    const float* __restrict__ W1, const float* __restrict__ B1, const float* __restrict__ G1, const float* __restrict__ E1,
    const float* __restrict__ W2, const float* __restrict__ B2, const float* __restrict__ G2, const float* __restrict__ E2,
    const float* __restrict__ Aatt,
    float* __restrict__ mfeat, float* __restrict__ P, int* __restrict__ cidx,
    int* __restrict__ done,
    float* __restrict__ X, float* __restrict__ Y, float* __restrict__ Z,
    float* __restrict__ out) {
  __shared__ __align__(16) char smem[F1_SMEM];
  if (blockIdx.x < 8)
    fps_body(smem, pts, cidx, X, Y, Z);
  else if (blockIdx.x < 72)
    projmlp_body(smem, pts, W0, B0, G0, E0, W1, B1, G1, E1, W2, B2, G2, E2,
                 Aatt, mfeat, P, done);
  else
    consumer_body(smem, X, Y, Z, mfeat, P, cidx, done, out, blockIdx.x - 72);
}

// Re-initializes the handshake state every launch (workspace may be poisoned
// between runs). Kernel boundary flushes these before mega starts.
__global__ __launch_bounds__(256) void init_kernel(int* __restrict__ cidx,
                                                   int* __restrict__ done) {
  int i = blockIdx.x * 256 + threadIdx.x;
  if (i < NBATCH * NPOINT) cidx[i] = -1;
  if (i < NBATCH) done[i] = 0;
}

// ---------------------------------------------------------------------------
extern "C" void kernel_launch(void* const* d_in, const int* in_sizes, int n_in,
                              void* d_out, int out_size, void* d_ws, size_t ws_size,
                              hipStream_t stream) {
  const float* points = (const float*)d_in[0];
  const float* W0 = (const float*)d_in[1];
  const float* B0 = (const float*)d_in[2];
  const float* G0 = (const float*)d_in[3];
  const float* E0 = (const float*)d_in[4];
  const float* W1 = (const float*)d_in[5];
  const float* B1 = (const float*)d_in[6];
  const float* G1 = (const float*)d_in[7];
  const float* E1 = (const float*)d_in[8];
  const float* W2 = (const float*)d_in[9];
  const float* B2 = (const float*)d_in[10];
  const float* G2 = (const float*)d_in[11];
  const float* E2 = (const float*)d_in[12];
  const float* Aatt = (const float*)d_in[13];
  float* out = (float*)d_out;

  // workspace (floats): mfeat 4.19M | P 4.19M | X/Y/Z 3*32k | cidx 8k | done 8
  float* mfeat = (float*)d_ws;
  float* Pw = mfeat + (size_t)NBATCH * NPTS * 128;
  float* Xw = Pw + (size_t)NBATCH * NPTS * 128;
  float* Yw = Xw + NBATCH * NPTS;
  float* Zw = Yw + NBATCH * NPTS;
  int* cidxw = (int*)(Zw + NBATCH * NPTS);
  int* donew = cidxw + NBATCH * NPOINT;

  init_kernel<<<32, 256, 0, stream>>>(cidxw, donew);
  mega_kernel<<<8 + 64 + NCONS, 256, 0, stream>>>(points,
      W0, B0, G0, E0, W1, B1, G1, E1, W2, B2, G2, E2, Aatt,
      mfeat, Pw, cidxw, donew, Xw, Yw, Zw, out);
}

// Round 8
// 839.073 us; speedup vs baseline: 1.6198x; 1.6198x over previous
//
#include <hip/hip_runtime.h>
#include <math.h>

#define NBATCH 8
#define NPTS 4096
#define NPOINT 1024
#define NSAMPLE 32
#define PTDIM 67        // 3 xyz + 64 feat
#define BIGF 1e10f

// DPP ctrl encodings (gfx9/CDNA)
#define DPP_QUAD_XOR1 0xB1   // quad_perm [1,0,3,2]
#define DPP_QUAD_XOR2 0x4E   // quad_perm [2,3,0,1]
#define DPP_ROW_HALF_MIRROR 0x141
#define DPP_ROW_MIRROR 0x140
#define DPP_ROW_BCAST15 0x142
#define DPP_ROW_BCAST31 0x143

template <int CTRL>
__device__ inline float dpp_mov_f(float v) {
  int i = __float_as_int(v);
  return __int_as_float(__builtin_amdgcn_update_dpp(i, i, CTRL, 0xf, 0xf, false));
}
template <int CTRL>
__device__ inline unsigned dpp_mov_u(unsigned v) {
  return (unsigned)__builtin_amdgcn_update_dpp((int)v, (int)v, CTRL, 0xf, 0xf, false);
}
template <int CTRL>
__device__ inline void dpp_min2(unsigned& hi, unsigned& lo) {
  unsigned nh = dpp_mov_u<CTRL>(hi);
  unsigned nl = dpp_mov_u<CTRL>(lo);
  bool take = (nh < hi) || (nh == hi && nl < lo);
  hi = take ? nh : hi;
  lo = take ? nl : lo;
}
__device__ inline unsigned fmap(float d) {
  unsigned b = __float_as_uint(d);
  return ((int)b < 0) ? ~b : (b | 0x80000000u);
}
#define FMAP_INF 0xFF800000u   // fmap(+INF)

// 32-lane-group reductions: 4 VALU-DPP levels + ONE shfl (xor16) per value.
__device__ inline float red32_max(float v) {
  v = fmaxf(v, dpp_mov_f<DPP_QUAD_XOR1>(v));
  v = fmaxf(v, dpp_mov_f<DPP_QUAD_XOR2>(v));
  v = fmaxf(v, dpp_mov_f<DPP_ROW_HALF_MIRROR>(v));
  v = fmaxf(v, dpp_mov_f<DPP_ROW_MIRROR>(v));
  v = fmaxf(v, __shfl_xor(v, 16));
  return v;
}
__device__ inline float red32_sum(float v) {
  v += dpp_mov_f<DPP_QUAD_XOR1>(v);
  v += dpp_mov_f<DPP_QUAD_XOR2>(v);
  v += dpp_mov_f<DPP_ROW_HALF_MIRROR>(v);
  v += dpp_mov_f<DPP_ROW_MIRROR>(v);
  v += __shfl_xor(v, 16);
  return v;
}

// ---------------------------------------------------------------------------
// F1: fused FPS (blocks 0..7; also emits SoA xyz) + PROJ-MLP (blocks 8..71).
// ROUND-0 VERBATIM — measured 650 us steady-state, bit-exact. No atomics,
// no cross-kernel handshakes (rounds 3-7 proved the producer/consumer
// overlap unprofitable: best 980 vs this architecture's 835).
// ---------------------------------------------------------------------------
struct FpsS {
  unsigned long long slots[2][4];
  int cidxS[NPOINT];
  float4 C[NPTS];
};
struct ProjS {
  float As[131 * 128];                             // a_att row-major
  float w0[64 * 64], w1[64 * 64], w2[128 * 64];
  float bb0[64], ss0[64], ee0[64];
  float bb1[64], ss1[64], ee1[64];
  float bb2[128], ss2[128], ee2[128];
};
#define F1_SMEM (sizeof(ProjS) > sizeof(FpsS) ? sizeof(ProjS) : sizeof(FpsS))

// FPS: one block per batch, 256 thr, 16 pts/lane, pk-f32 dist update under
// contract(off) (IEEE-identical per component). Split-phase DPP argmax.
// Exact f32 replication of jnp: ((dx*dx+dy*dy)+dz*dz), min, argmax first-idx.
__device__ void fps_body(char* smemRaw, const float* __restrict__ pts,
                         int* __restrict__ cidx, float* __restrict__ X,
                         float* __restrict__ Y, float* __restrict__ Z) {
#pragma clang fp contract(off)
  FpsS* S = (FpsS*)smemRaw;
  const int b = blockIdx.x, tid = threadIdx.x;
  const int w = tid >> 6, lane = tid & 63;
  const float* pb = pts + (size_t)b * NPTS * PTDIM;
  float2 px2[8], py2[8], pz2[8];
  float dl[16];
  #pragma unroll
  for (int k = 0; k < 16; k++) {
    int j = tid + (k << 8);
    const float* pj = pb + (size_t)j * PTDIM;
    float x = pj[0], y = pj[1], z = pj[2];
    if (k & 1) { px2[k >> 1].y = x; py2[k >> 1].y = y; pz2[k >> 1].y = z; }
    else       { px2[k >> 1].x = x; py2[k >> 1].x = y; pz2[k >> 1].x = z; }
    S->C[j] = make_float4(x, y, z, 0.0f);
    X[b * NPTS + j] = x; Y[b * NPTS + j] = y; Z[b * NPTS + j] = z;  // SoA out
    dl[k] = BIGF;
  }
  __syncthreads();
  int f = 0;
  float4 c0 = S->C[0];
  float cx = c0.x, cy = c0.y, cz = c0.z;
  for (int t = 0; t < NPOINT; t++) {
    if (tid == 0) S->cidxS[t] = f;                 // emit BEFORE update
    float2 c2x = make_float2(cx, cx);
    float2 c2y = make_float2(cy, cy);
    float2 c2z = make_float2(cz, cz);
    #pragma unroll
    for (int m = 0; m < 8; m++) {
      float2 dx = px2[m] - c2x;
      float2 dy = py2[m] - c2y;
      float2 dz = pz2[m] - c2z;
      float2 d = (dx * dx + dy * dy) + dz * dz;    // pk ops, contract OFF
      dl[2 * m]     = fminf(dl[2 * m],     d.x);
      dl[2 * m + 1] = fminf(dl[2 * m + 1], d.y);
    }
    float u0 = fmaxf(dl[0], dl[1]),  u1 = fmaxf(dl[2], dl[3]);
    float u2 = fmaxf(dl[4], dl[5]),  u3 = fmaxf(dl[6], dl[7]);
    float u4 = fmaxf(dl[8], dl[9]),  u5 = fmaxf(dl[10], dl[11]);
    float u6 = fmaxf(dl[12], dl[13]), u7 = fmaxf(dl[14], dl[15]);
    float v0 = fmaxf(u0, u1), v1 = fmaxf(u2, u3);
    float v2 = fmaxf(u4, u5), v3 = fmaxf(u6, u7);
    float bv = fmaxf(fmaxf(v0, v1), fmaxf(v2, v3));
    float m = bv;
    m = fmaxf(m, dpp_mov_f<DPP_QUAD_XOR1>(m));
    m = fmaxf(m, dpp_mov_f<DPP_QUAD_XOR2>(m));
    m = fmaxf(m, dpp_mov_f<DPP_ROW_HALF_MIRROR>(m));
    m = fmaxf(m, dpp_mov_f<DPP_ROW_MIRROR>(m));
    m = fmaxf(m, dpp_mov_f<DPP_ROW_BCAST15>(m));
    m = fmaxf(m, dpp_mov_f<DPP_ROW_BCAST31>(m));   // lane63 = wave max
    unsigned wmaxbits = (unsigned)__builtin_amdgcn_readlane(__float_as_int(m), 63);
    // min index among holders (bit-equality exact: no -0 from sums of squares)
    unsigned c_[16];
    #pragma unroll
    for (int k = 0; k < 16; k++)
      c_[k] = (__float_as_uint(dl[k]) == wmaxbits) ? (unsigned)(tid + (k << 8)) : 0xFFFFFFFFu;
    unsigned q0 = min(c_[0], c_[1]),  q1 = min(c_[2], c_[3]);
    unsigned q2 = min(c_[4], c_[5]),  q3 = min(c_[6], c_[7]);
    unsigned q4 = min(c_[8], c_[9]),  q5 = min(c_[10], c_[11]);
    unsigned q6 = min(c_[12], c_[13]), q7 = min(c_[14], c_[15]);
    unsigned r0 = min(q0, q1), r1 = min(q2, q3), r2 = min(q4, q5), r3 = min(q6, q7);
    unsigned cand = min(min(r0, r1), min(r2, r3));
    cand = min(cand, dpp_mov_u<DPP_QUAD_XOR1>(cand));
    cand = min(cand, dpp_mov_u<DPP_QUAD_XOR2>(cand));
    cand = min(cand, dpp_mov_u<DPP_ROW_HALF_MIRROR>(cand));
    cand = min(cand, dpp_mov_u<DPP_ROW_MIRROR>(cand));
    cand = min(cand, dpp_mov_u<DPP_ROW_BCAST15>(cand));
    cand = min(cand, dpp_mov_u<DPP_ROW_BCAST31>(cand));  // lane63 = min j
    unsigned jmin = (unsigned)__builtin_amdgcn_readlane((int)cand, 63);
    if (lane == 0)
      S->slots[t & 1][w] = ((unsigned long long)wmaxbits << 32) |
                           (unsigned long long)(NPTS - 1 - jmin);
    __syncthreads();
    unsigned long long s0 = S->slots[t & 1][0], s1 = S->slots[t & 1][1];
    unsigned long long s2 = S->slots[t & 1][2], s3 = S->slots[t & 1][3];
    unsigned long long m0 = s0 > s1 ? s0 : s1;
    unsigned long long m1 = s2 > s3 ? s2 : s3;
    unsigned long long best = m0 > m1 ? m0 : m1;
    f = NPTS - 1 - (int)(best & 0xFFFFFFFFull);
    float4 cc = S->C[f];
    cx = cc.x; cy = cc.y; cz = cc.z;
  }
  __syncthreads();
  for (int i = tid; i < NPOINT; i += 256) cidx[b * NPOINT + i] = S->cidxS[i];
}

// PROJ-MLP: 64 blocks x 512 rows (2 rows/thread, sequential). Round-0
// verbatim: all weights + A staged in LDS; op order bit-identical.
__device__ void projmlp_body(char* smemRaw, const float* __restrict__ pts,
    const float* __restrict__ W0, const float* __restrict__ B0, const float* __restrict__ G0, const float* __restrict__ E0,
    const float* __restrict__ W1, const float* __restrict__ B1, const float* __restrict__ G1, const float* __restrict__ E1,
    const float* __restrict__ W2, const float* __restrict__ B2, const float* __restrict__ G2, const float* __restrict__ E2,
    const float* __restrict__ Aatt,
    float* __restrict__ mfeat, float* __restrict__ P) {
  ProjS* S = (ProjS*)smemRaw;
  const float INVS = 0.99999500003750f;            // 1/sqrt(1+1e-5)
  const int t = threadIdx.x;
  for (int i = t; i < 131 * 128; i += 256) S->As[i] = Aatt[i];
  for (int i = t; i < 4096; i += 256) { S->w0[i] = W0[i]; S->w1[i] = W1[i]; }
  for (int i = t; i < 8192; i += 256) S->w2[i] = W2[i];
  if (t < 64) {
    S->bb0[t] = B0[t]; S->ss0[t] = G0[t] * INVS; S->ee0[t] = E0[t];
    S->bb1[t] = B1[t]; S->ss1[t] = G1[t] * INVS; S->ee1[t] = E1[t];
  }
  if (t < 128) { S->bb2[t] = B2[t]; S->ss2[t] = G2[t] * INVS; S->ee2[t] = E2[t]; }
  __syncthreads();

  const int pb = blockIdx.x - 8;                   // 0..63
  for (int rr = 0; rr < 2; rr++) {
    const size_t r = (size_t)pb * 512 + rr * 256 + t;   // row 0..32767
    const float* xr = pts + r * PTDIM + 3;
    float x[64];
    #pragma unroll
    for (int c = 0; c < 64; c++) x[c] = xr[c];

    float h1[64];
    #pragma unroll
    for (int o = 0; o < 64; o++) {
      float acc = S->bb0[o];
      #pragma unroll
      for (int c = 0; c < 64; c += 4) {
        float4 wv = *(const float4*)&S->w0[o * 64 + c];
        acc = fmaf(wv.x, x[c], acc);
        acc = fmaf(wv.y, x[c + 1], acc);
        acc = fmaf(wv.z, x[c + 2], acc);
        acc = fmaf(wv.w, x[c + 3], acc);
      }
      h1[o] = fmaxf(fmaf(acc, S->ss0[o], S->ee0[o]), 0.0f);
    }
    float h2[64];
    #pragma unroll
    for (int o = 0; o < 64; o++) {
      float acc = S->bb1[o];
      #pragma unroll
      for (int c = 0; c < 64; c += 4) {
        float4 wv = *(const float4*)&S->w1[o * 64 + c];
        acc = fmaf(wv.x, h1[c], acc);
        acc = fmaf(wv.y, h1[c + 1], acc);
        acc = fmaf(wv.z, h1[c + 2], acc);
        acc = fmaf(wv.w, h1[c + 3], acc);
      }
      h2[o] = fmaxf(fmaf(acc, S->ss1[o], S->ee1[o]), 0.0f);
    }
    float h3[128];
    float* orow = mfeat + r * 128;
    #pragma unroll
    for (int o = 0; o < 128; o += 4) {
      float a0 = S->bb2[o], a1 = S->bb2[o + 1], a2 = S->bb2[o + 2], a3 = S->bb2[o + 3];
      #pragma unroll
      for (int c = 0; c < 64; c += 4) {
        float4 wv0 = *(const float4*)&S->w2[(o    ) * 64 + c];
        float4 wv1 = *(const float4*)&S->w2[(o + 1) * 64 + c];
        float4 wv2 = *(const float4*)&S->w2[(o + 2) * 64 + c];
        float4 wv3 = *(const float4*)&S->w2[(o + 3) * 64 + c];
        a0 = fmaf(wv0.x, h2[c], a0); a0 = fmaf(wv0.y, h2[c+1], a0); a0 = fmaf(wv0.z, h2[c+2], a0); a0 = fmaf(wv0.w, h2[c+3], a0);
        a1 = fmaf(wv1.x, h2[c], a1); a1 = fmaf(wv1.y, h2[c+1], a1); a1 = fmaf(wv1.z, h2[c+2], a1); a1 = fmaf(wv1.w, h2[c+3], a1);
        a2 = fmaf(wv2.x, h2[c], a2); a2 = fmaf(wv2.y, h2[c+1], a2); a2 = fmaf(wv2.z, h2[c+2], a2); a2 = fmaf(wv2.w, h2[c+3], a2);
        a3 = fmaf(wv3.x, h2[c], a3); a3 = fmaf(wv3.y, h2[c+1], a3); a3 = fmaf(wv3.z, h2[c+2], a3); a3 = fmaf(wv3.w, h2[c+3], a3);
      }
      float4 ov;
      ov.x = fmaxf(fmaf(a0, S->ss2[o    ], S->ee2[o    ]), 0.0f);
      ov.y = fmaxf(fmaf(a1, S->ss2[o + 1], S->ee2[o + 1]), 0.0f);
      ov.z = fmaxf(fmaf(a2, S->ss2[o + 2], S->ee2[o + 2]), 0.0f);
      ov.w = fmaxf(fmaf(a3, S->ss2[o + 3], S->ee2[o + 3]), 0.0f);
      h3[o] = ov.x; h3[o + 1] = ov.y; h3[o + 2] = ov.z; h3[o + 3] = ov.w;
      *(float4*)(orow + o) = ov;
    }
    // P row = [xyz, h3] @ A   (ascending-c order, identical to round-0)
    const float* pr = pts + r * PTDIM;
    float x0 = pr[0], y0 = pr[1], z0 = pr[2];
    float* prow = P + r * 128;
    for (int grp = 0; grp < 4; grp++) {
      const int g0 = grp * 32;
      float acc[32];
      #pragma unroll
      for (int j = 0; j < 32; j++) {
        float a0 = S->As[0 * 128 + g0 + j];
        float a1 = S->As[1 * 128 + g0 + j];
        float a2 = S->As[2 * 128 + g0 + j];
        acc[j] = fmaf(z0, a2, fmaf(y0, a1, x0 * a0));
      }
      #pragma unroll
      for (int c = 0; c < 128; c++) {
        float s = h3[c];
        const float* arow = &S->As[(3 + c) * 128 + g0];
        #pragma unroll
        for (int j = 0; j < 32; j += 4) {
          float4 a = *(const float4*)&arow[j];
          acc[j]   = fmaf(s, a.x, acc[j]);
          acc[j+1] = fmaf(s, a.y, acc[j+1]);
          acc[j+2] = fmaf(s, a.z, acc[j+2]);
          acc[j+3] = fmaf(s, a.w, acc[j+3]);
        }
      }
      #pragma unroll
      for (int j = 0; j < 32; j += 4)
        *(float4*)(prow + g0 + j) = make_float4(acc[j], acc[j+1], acc[j+2], acc[j+3]);
    }
  }
}

__global__ __launch_bounds__(256) void f1_kernel(const float* __restrict__ pts,
    const float* __restrict__ W0, const float* __restrict__ B0, const float* __restrict__ G0, const float* __restrict__ E0,
    const float* __restrict__ W1, const float* __restrict__ B1, const float* __restrict__ G1, const float* __restrict__ E1,
    const float* __restrict__ W2, const float* __restrict__ B2, const float* __restrict__ G2, const float* __restrict__ E2,
    const float* __restrict__ Aatt,
    float* __restrict__ mfeat, float* __restrict__ P, int* __restrict__ cidx,
    float* __restrict__ X, float* __restrict__ Y, float* __restrict__ Z) {
  __shared__ __align__(16) char smem[F1_SMEM];
  if (blockIdx.x < 8)
    fps_body(smem, pts, cidx, X, Y, Z);
  else
    projmlp_body(smem, pts, W0, B0, G0, E0, W1, B1, G1, E1, W2, B2, G2, E2,
                 Aatt, mfeat, P);
}

// ---------------------------------------------------------------------------
// F2ATTN: fused ball query + attention. 2048 blocks, 4 waves each; wave w
// ball-queries center grp*4+w (exact f2 code; gidx stays in LDS — no global
// round trip), then the block runs attention for its 4 centers (exact attn
// code, verified at this 256-thread shape in rounds 4-7). Batch-per-XCD
// swizzle (b = blockIdx&7) covers BOTH phases. vs split kernels: one launch
// boundary fewer, 8192->2048 blocks (4x per-block amortization, one full
// residency generation at 8 blk/CU instead of four).
// ---------------------------------------------------------------------------
__global__ __launch_bounds__(256) void f2attn_kernel(
    const float* __restrict__ X, const float* __restrict__ Y, const float* __restrict__ Z,
    const float* __restrict__ mfeat, const float* __restrict__ P,
    const int* __restrict__ cidx, float* __restrict__ out) {
  __shared__ float dbuf[4][512];
  __shared__ int   ibuf[4][512];
  __shared__ int   gidxS[4][32];
  __shared__ int   cIS[4];
  __shared__ float pcS[128];
  const int t = threadIdx.x;
  const int w = t >> 6, lane = t & 63;
  const int b = blockIdx.x & 7;                    // batch-per-XCD swizzle
  const int grp = blockIdx.x >> 3;                 // 0..255
  const int pc = b * NPOINT + grp * 4 + w;         // this wave's center
  const float* Xb = X + b * NPTS;
  const float* Yb = Y + b * NPTS;
  const float* Zb = Z + b * NPTS;
  const float R2 = 0.04f;

  // --- ball query (exact f2 algorithm, per wave) ---
  const int cI = cidx[pc];
  if (lane == 0) cIS[w] = cI;
  const float cx = Xb[cI], cy = Yb[cI], cz = Zb[cI];
  const float sc = __fadd_rn(__fadd_rn(__fmul_rn(cx, cx), __fmul_rn(cy, cy)), __fmul_rn(cz, cz));
  int cnt = 0;                                     // wave-uniform
  for (int rr = 0; rr < 16; rr++) {
    const int base = rr * 256 + lane * 4;
    float4 px4 = *(const float4*)(Xb + base);
    float4 py4 = *(const float4*)(Yb + base);
    float4 pz4 = *(const float4*)(Zb + base);
    #pragma unroll
    for (int e = 0; e < 4; e++) {
      float px = e == 0 ? px4.x : e == 1 ? px4.y : e == 2 ? px4.z : px4.w;
      float py = e == 0 ? py4.x : e == 1 ? py4.y : e == 2 ? py4.z : py4.w;
      float pz = e == 0 ? pz4.x : e == 1 ? pz4.y : e == 2 ? pz4.z : pz4.w;
      float dot = __fadd_rn(__fadd_rn(__fmul_rn(cx, px), __fmul_rn(cy, py)), __fmul_rn(cz, pz));
      float sx  = __fadd_rn(__fadd_rn(__fmul_rn(px, px), __fmul_rn(py, py)), __fmul_rn(pz, pz));
      float d   = __fadd_rn(__fadd_rn(__fmul_rn(-2.0f, dot), sc), sx);
      bool pred = !(d > R2);
      unsigned long long mask = __ballot(pred);
      if (pred) {
        int pos = cnt + (int)__popcll(mask & ((1ull << lane) - 1ull));
        if (pos < 512) { dbuf[w][pos] = d; ibuf[w][pos] = base + e; }
      }
      cnt += (int)__popcll(mask);
    }
  }
  const int K = cnt < 512 ? cnt : 512;
  unsigned long long kk[8];
  #pragma unroll
  for (int kq = 0; kq < 8; kq++) {
    int pos = lane + 64 * kq;
    if (pos < K)
      kk[kq] = ((unsigned long long)fmap(dbuf[w][pos]) << 32) | (unsigned)ibuf[w][pos];
    else
      kk[kq] = ((unsigned long long)FMAP_INF << 32) | 0x7fffffffu;
  }
  int first = 0;
  for (int it = 0; it < NSAMPLE; it++) {
    unsigned long long best = kk[0];
    #pragma unroll
    for (int kq = 1; kq < 8; kq++) if (kk[kq] < best) best = kk[kq];
    unsigned hi = (unsigned)(best >> 32), lo = (unsigned)best;
    dpp_min2<DPP_QUAD_XOR1>(hi, lo);
    dpp_min2<DPP_QUAD_XOR2>(hi, lo);
    dpp_min2<DPP_ROW_HALF_MIRROR>(hi, lo);
    dpp_min2<DPP_ROW_MIRROR>(hi, lo);
    dpp_min2<DPP_ROW_BCAST15>(hi, lo);
    dpp_min2<DPP_ROW_BCAST31>(hi, lo);             // lane63 = wave min
    unsigned blo = (unsigned)__builtin_amdgcn_readlane((int)lo, 63);
    #pragma unroll
    for (int kq = 0; kq < 8; kq++)
      if ((unsigned)kk[kq] == blo)
        kk[kq] = (kk[kq] & 0xFFFFFFFFull) | ((unsigned long long)FMAP_INF << 32);
    if (it == 0) first = (int)blo;
    if (lane == 0) gidxS[w][it] = (it < K) ? (int)blo : first;
  }
  __syncthreads();                                 // gidxS/cIS visible to block

  // --- attention for the block's 4 centers (exact attn algorithm) ---
  for (int cc = 0; cc < 4; cc++) {
    const int pcc = b * NPOINT + grp * 4 + cc;
    const int cIc = cIS[cc];
    if (t < 128) pcS[t] = P[((size_t)b * NPTS + cIc) * 128 + t];
    __syncthreads();
    const int n = t & 31, q = t >> 5;              // q: 0..7, 16 channels each
    const int g = gidxS[cc][n];
    const float* Pg = P + ((size_t)b * NPTS + g) * 128 + q * 16;
    const float* Gf = mfeat + ((size_t)b * NPTS + g) * 128 + q * 16;
    float a[16], gfv[16];
    #pragma unroll
    for (int kq = 0; kq < 4; kq++) {
      float4 vg = *(const float4*)(Pg + 4 * kq);
      float4 vc = *(const float4*)&pcS[q * 16 + 4 * kq];   // LDS broadcast
      float4 vf = *(const float4*)(Gf + 4 * kq);
      a[4*kq]   = vg.x - vc.x; a[4*kq+1] = vg.y - vc.y;
      a[4*kq+2] = vg.z - vc.z; a[4*kq+3] = vg.w - vc.w;
      gfv[4*kq] = vf.x; gfv[4*kq+1] = vf.y; gfv[4*kq+2] = vf.z; gfv[4*kq+3] = vf.w;
    }
    #pragma unroll
    for (int j = 0; j < 16; j++) a[j] = a[j] >= 0.0f ? a[j] : 0.2f * a[j];
    float e[16], s[16], num[16];
    #pragma unroll
    for (int j = 0; j < 16; j++) {
      float mx = red32_max(a[j]);
      e[j] = expf(a[j] - mx);
    }
    #pragma unroll
    for (int j = 0; j < 16; j++) s[j] = red32_sum(e[j]);
    #pragma unroll
    for (int j = 0; j < 16; j++) num[j] = red32_sum(e[j] * gfv[j]);
    if (n == 0) {
      float* orow = out + (size_t)pcc * 131;
      #pragma unroll
      for (int j = 0; j < 16; j++) orow[3 + q * 16 + j] = num[j] / s[j];
      if (q == 0) {
        orow[0] = Xb[cIc]; orow[1] = Yb[cIc]; orow[2] = Zb[cIc];
      }
    }
    __syncthreads();                               // pcS reuse barrier
  }
}

// ---------------------------------------------------------------------------
extern "C" void kernel_launch(void* const* d_in, const int* in_sizes, int n_in,
                              void* d_out, int out_size, void* d_ws, size_t ws_size,
                              hipStream_t stream) {
  const float* points = (const float*)d_in[0];
  const float* W0 = (const float*)d_in[1];
  const float* B0 = (const float*)d_in[2];
  const float* G0 = (const float*)d_in[3];
  const float* E0 = (const float*)d_in[4];
  const float* W1 = (const float*)d_in[5];
  const float* B1 = (const float*)d_in[6];
  const float* G1 = (const float*)d_in[7];
  const float* E1 = (const float*)d_in[8];
  const float* W2 = (const float*)d_in[9];
  const float* B2 = (const float*)d_in[10];
  const float* G2 = (const float*)d_in[11];
  const float* E2 = (const float*)d_in[12];
  const float* Aatt = (const float*)d_in[13];
  float* out = (float*)d_out;

  // workspace (floats): mfeat 4.19M | P 4.19M | X/Y/Z 3*32k | cidx 8k  (~34 MB)
  float* mfeat = (float*)d_ws;
  float* Pw = mfeat + (size_t)NBATCH * NPTS * 128;
  float* Xw = Pw + (size_t)NBATCH * NPTS * 128;
  float* Yw = Xw + NBATCH * NPTS;
  float* Zw = Yw + NBATCH * NPTS;
  int* cidxw = (int*)(Zw + NBATCH * NPTS);

  f1_kernel<<<8 + 64, 256, 0, stream>>>(points,
      W0, B0, G0, E0, W1, B1, G1, E1, W2, B2, G2, E2, Aatt,
      mfeat, Pw, cidxw, Xw, Yw, Zw);
  f2attn_kernel<<<NBATCH * NPOINT / 4, 256, 0, stream>>>(Xw, Yw, Zw,
      mfeat, Pw, cidxw, out);
}

// Round 9
// 794.448 us; speedup vs baseline: 1.7108x; 1.0562x over previous
//
#include <hip/hip_runtime.h>
#include <math.h>

#define NBATCH 8
#define NPTS 4096
#define NPOINT 1024
#define NSAMPLE 32
#define PTDIM 67        // 3 xyz + 64 feat
#define BIGF 1e10f

// DPP ctrl encodings (gfx9/CDNA)
#define DPP_QUAD_XOR1 0xB1   // quad_perm [1,0,3,2]
#define DPP_QUAD_XOR2 0x4E   // quad_perm [2,3,0,1]
#define DPP_ROW_HALF_MIRROR 0x141
#define DPP_ROW_MIRROR 0x140
#define DPP_ROW_BCAST15 0x142
#define DPP_ROW_BCAST31 0x143

template <int CTRL>
__device__ inline float dpp_mov_f(float v) {
  int i = __float_as_int(v);
  return __int_as_float(__builtin_amdgcn_update_dpp(i, i, CTRL, 0xf, 0xf, false));
}
template <int CTRL>
__device__ inline unsigned dpp_mov_u(unsigned v) {
  return (unsigned)__builtin_amdgcn_update_dpp((int)v, (int)v, CTRL, 0xf, 0xf, false);
}
template <int CTRL>
__device__ inline void dpp_min2(unsigned& hi, unsigned& lo) {
  unsigned nh = dpp_mov_u<CTRL>(hi);
  unsigned nl = dpp_mov_u<CTRL>(lo);
  bool take = (nh < hi) || (nh == hi && nl < lo);
  hi = take ? nh : hi;
  lo = take ? nl : lo;
}
// Pair-key MAX step for FPS argmax: key = (hi=dbits, lo=4095-j), u64 compare.
// 2 dpp_mov + v_cmp_gt_u64 + 2 cndmask per level (f2's proven dpp_min2 shape).
template <int CTRL>
__device__ inline void dpp_max2(unsigned& hi, unsigned& lo) {
  unsigned nh = dpp_mov_u<CTRL>(hi);
  unsigned nl = dpp_mov_u<CTRL>(lo);
  unsigned long long k0 = ((unsigned long long)hi << 32) | lo;
  unsigned long long k1 = ((unsigned long long)nh << 32) | nl;
  bool take = k1 > k0;
  hi = take ? nh : hi;
  lo = take ? nl : lo;
}
__device__ inline unsigned fmap(float d) {
  unsigned b = __float_as_uint(d);
  return ((int)b < 0) ? ~b : (b | 0x80000000u);
}
#define FMAP_INF 0xFF800000u   // fmap(+INF)

// 32-lane-group reductions: 4 VALU-DPP levels + ONE shfl (xor16) per value.
__device__ inline float red32_max(float v) {
  v = fmaxf(v, dpp_mov_f<DPP_QUAD_XOR1>(v));
  v = fmaxf(v, dpp_mov_f<DPP_QUAD_XOR2>(v));
  v = fmaxf(v, dpp_mov_f<DPP_ROW_HALF_MIRROR>(v));
  v = fmaxf(v, dpp_mov_f<DPP_ROW_MIRROR>(v));
  v = fmaxf(v, __shfl_xor(v, 16));
  return v;
}
__device__ inline float red32_sum(float v) {
  v += dpp_mov_f<DPP_QUAD_XOR1>(v);
  v += dpp_mov_f<DPP_QUAD_XOR2>(v);
  v += dpp_mov_f<DPP_ROW_HALF_MIRROR>(v);
  v += dpp_mov_f<DPP_ROW_MIRROR>(v);
  v += __shfl_xor(v, 16);
  return v;
}

// ---------------------------------------------------------------------------
// F1: fused FPS (blocks 0..7; also emits SoA xyz) + PROJ-MLP (blocks 8..71).
// FPS argmax: SINGLE pair-key DPP chain (d, 4095-j) replacing the two-phase
// {max-chain, readlane, holder-compare, idx-chain, readlane}. Removes ~60
// instr + 2 SGPR-broadcast stalls per serial iteration; slot encoding and
// all selection semantics bit-identical to the 650us round-0 kernel.
// ---------------------------------------------------------------------------
struct FpsS {
  unsigned long long slots[2][4];
  int cidxS[NPOINT];
  float4 C[NPTS];
};
struct ProjS {
  float As[131 * 128];                             // a_att row-major
  float w0[64 * 64], w1[64 * 64], w2[128 * 64];
  float bb0[64], ss0[64], ee0[64];
  float bb1[64], ss1[64], ee1[64];
  float bb2[128], ss2[128], ee2[128];
};
#define F1_SMEM (sizeof(ProjS) > sizeof(FpsS) ? sizeof(ProjS) : sizeof(FpsS))

// FPS: one block per batch, 256 thr, 16 pts/lane, pk-f32 dist update under
// contract(off) (IEEE-identical per component). Exact f32 replication of
// jnp: ((dx*dx+dy*dy)+dz*dz), min, argmax first-idx.
__device__ void fps_body(char* smemRaw, const float* __restrict__ pts,
                         int* __restrict__ cidx, float* __restrict__ X,
                         float* __restrict__ Y, float* __restrict__ Z) {
#pragma clang fp contract(off)
  FpsS* S = (FpsS*)smemRaw;
  const int b = blockIdx.x, tid = threadIdx.x;
  const int w = tid >> 6, lane = tid & 63;
  const float* pb = pts + (size_t)b * NPTS * PTDIM;
  float2 px2[8], py2[8], pz2[8];
  float dl[16];
  #pragma unroll
  for (int k = 0; k < 16; k++) {
    int j = tid + (k << 8);
    const float* pj = pb + (size_t)j * PTDIM;
    float x = pj[0], y = pj[1], z = pj[2];
    if (k & 1) { px2[k >> 1].y = x; py2[k >> 1].y = y; pz2[k >> 1].y = z; }
    else       { px2[k >> 1].x = x; py2[k >> 1].x = y; pz2[k >> 1].x = z; }
    S->C[j] = make_float4(x, y, z, 0.0f);
    X[b * NPTS + j] = x; Y[b * NPTS + j] = y; Z[b * NPTS + j] = z;  // SoA out
    dl[k] = BIGF;
  }
  __syncthreads();
  const unsigned jb = 4095u - (unsigned)tid;       // jp(k) = jb - (k<<8)
  int f = 0;
  float4 c0 = S->C[0];
  float cx = c0.x, cy = c0.y, cz = c0.z;
  for (int t = 0; t < NPOINT; t++) {
    if (tid == 0) S->cidxS[t] = f;                 // emit BEFORE update
    float2 c2x = make_float2(cx, cx);
    float2 c2y = make_float2(cy, cy);
    float2 c2z = make_float2(cz, cz);
    #pragma unroll
    for (int m = 0; m < 8; m++) {
      float2 dx = px2[m] - c2x;
      float2 dy = py2[m] - c2y;
      float2 dz = pz2[m] - c2z;
      float2 d = (dx * dx + dy * dy) + dz * dz;    // pk ops, contract OFF
      dl[2 * m]     = fminf(dl[2 * m],     d.x);
      dl[2 * m + 1] = fminf(dl[2 * m + 1], d.y);
    }
    // Local 16 -> 1 argmax carrying (d, jp=4095-j). Strict '>' keeps LEFT on
    // ties == first index (j ascends with k). 3 instr per merge.
    float td[8]; unsigned tj[8];
    #pragma unroll
    for (int m = 0; m < 8; m++) {
      bool take = dl[2 * m + 1] > dl[2 * m];
      td[m] = take ? dl[2 * m + 1] : dl[2 * m];
      tj[m] = jb - (unsigned)((take ? (2 * m + 1) : (2 * m)) << 8);
    }
    #pragma unroll
    for (int m = 0; m < 4; m++) {
      bool take = td[2 * m + 1] > td[2 * m];
      td[m] = take ? td[2 * m + 1] : td[2 * m];
      tj[m] = take ? tj[2 * m + 1] : tj[2 * m];
    }
    #pragma unroll
    for (int m = 0; m < 2; m++) {
      bool take = td[2 * m + 1] > td[2 * m];
      td[m] = take ? td[2 * m + 1] : td[2 * m];
      tj[m] = take ? tj[2 * m + 1] : tj[2 * m];
    }
    {
      bool take = td[1] > td[0];
      td[0] = take ? td[1] : td[0];
      tj[0] = take ? tj[1] : tj[0];
    }
    // Wave 64 -> 1: single pair-key DPP chain. d >= 0 so float bits are
    // unsigned-monotone; jp in the low word resolves ties to min j exactly.
    unsigned hi = __float_as_uint(td[0]), lo = tj[0];
    dpp_max2<DPP_QUAD_XOR1>(hi, lo);
    dpp_max2<DPP_QUAD_XOR2>(hi, lo);
    dpp_max2<DPP_ROW_HALF_MIRROR>(hi, lo);
    dpp_max2<DPP_ROW_MIRROR>(hi, lo);
    dpp_max2<DPP_ROW_BCAST15>(hi, lo);
    dpp_max2<DPP_ROW_BCAST31>(hi, lo);             // lane63 = wave winner
    if (lane == 63)
      S->slots[t & 1][w] = ((unsigned long long)hi << 32) |
                           (unsigned long long)lo;  // same encoding as before
    __syncthreads();
    unsigned long long s0 = S->slots[t & 1][0], s1 = S->slots[t & 1][1];
    unsigned long long s2 = S->slots[t & 1][2], s3 = S->slots[t & 1][3];
    unsigned long long m0 = s0 > s1 ? s0 : s1;
    unsigned long long m1 = s2 > s3 ? s2 : s3;
    unsigned long long best = m0 > m1 ? m0 : m1;
    f = NPTS - 1 - (int)(best & 0xFFFFFFFFull);
    float4 cc = S->C[f];
    cx = cc.x; cy = cc.y; cz = cc.z;
  }
  __syncthreads();
  for (int i = tid; i < NPOINT; i += 256) cidx[b * NPOINT + i] = S->cidxS[i];
}

// PROJ-MLP: 64 blocks x 512 rows (2 rows/thread, sequential). Round-0
// verbatim: all weights + A staged in LDS; op order bit-identical.
__device__ void projmlp_body(char* smemRaw, const float* __restrict__ pts,
    const float* __restrict__ W0, const float* __restrict__ B0, const float* __restrict__ G0, const float* __restrict__ E0,
    const float* __restrict__ W1, const float* __restrict__ B1, const float* __restrict__ G1, const float* __restrict__ E1,
    const float* __restrict__ W2, const float* __restrict__ B2, const float* __restrict__ G2, const float* __restrict__ E2,
    const float* __restrict__ Aatt,
    float* __restrict__ mfeat, float* __restrict__ P) {
  ProjS* S = (ProjS*)smemRaw;
  const float INVS = 0.99999500003750f;            // 1/sqrt(1+1e-5)
  const int t = threadIdx.x;
  for (int i = t; i < 131 * 128; i += 256) S->As[i] = Aatt[i];
  for (int i = t; i < 4096; i += 256) { S->w0[i] = W0[i]; S->w1[i] = W1[i]; }
  for (int i = t; i < 8192; i += 256) S->w2[i] = W2[i];
  if (t < 64) {
    S->bb0[t] = B0[t]; S->ss0[t] = G0[t] * INVS; S->ee0[t] = E0[t];
    S->bb1[t] = B1[t]; S->ss1[t] = G1[t] * INVS; S->ee1[t] = E1[t];
  }
  if (t < 128) { S->bb2[t] = B2[t]; S->ss2[t] = G2[t] * INVS; S->ee2[t] = E2[t]; }
  __syncthreads();

  const int pb = blockIdx.x - 8;                   // 0..63
  for (int rr = 0; rr < 2; rr++) {
    const size_t r = (size_t)pb * 512 + rr * 256 + t;   // row 0..32767
    const float* xr = pts + r * PTDIM + 3;
    float x[64];
    #pragma unroll
    for (int c = 0; c < 64; c++) x[c] = xr[c];

    float h1[64];
    #pragma unroll
    for (int o = 0; o < 64; o++) {
      float acc = S->bb0[o];
      #pragma unroll
      for (int c = 0; c < 64; c += 4) {
        float4 wv = *(const float4*)&S->w0[o * 64 + c];
        acc = fmaf(wv.x, x[c], acc);
        acc = fmaf(wv.y, x[c + 1], acc);
        acc = fmaf(wv.z, x[c + 2], acc);
        acc = fmaf(wv.w, x[c + 3], acc);
      }
      h1[o] = fmaxf(fmaf(acc, S->ss0[o], S->ee0[o]), 0.0f);
    }
    float h2[64];
    #pragma unroll
    for (int o = 0; o < 64; o++) {
      float acc = S->bb1[o];
      #pragma unroll
      for (int c = 0; c < 64; c += 4) {
        float4 wv = *(const float4*)&S->w1[o * 64 + c];
        acc = fmaf(wv.x, h1[c], acc);
        acc = fmaf(wv.y, h1[c + 1], acc);
        acc = fmaf(wv.z, h1[c + 2], acc);
        acc = fmaf(wv.w, h1[c + 3], acc);
      }
      h2[o] = fmaxf(fmaf(acc, S->ss1[o], S->ee1[o]), 0.0f);
    }
    float h3[128];
    float* orow = mfeat + r * 128;
    #pragma unroll
    for (int o = 0; o < 128; o += 4) {
      float a0 = S->bb2[o], a1 = S->bb2[o + 1], a2 = S->bb2[o + 2], a3 = S->bb2[o + 3];
      #pragma unroll
      for (int c = 0; c < 64; c += 4) {
        float4 wv0 = *(const float4*)&S->w2[(o    ) * 64 + c];
        float4 wv1 = *(const float4*)&S->w2[(o + 1) * 64 + c];
        float4 wv2 = *(const float4*)&S->w2[(o + 2) * 64 + c];
        float4 wv3 = *(const float4*)&S->w2[(o + 3) * 64 + c];
        a0 = fmaf(wv0.x, h2[c], a0); a0 = fmaf(wv0.y, h2[c+1], a0); a0 = fmaf(wv0.z, h2[c+2], a0); a0 = fmaf(wv0.w, h2[c+3], a0);
        a1 = fmaf(wv1.x, h2[c], a1); a1 = fmaf(wv1.y, h2[c+1], a1); a1 = fmaf(wv1.z, h2[c+2], a1); a1 = fmaf(wv1.w, h2[c+3], a1);
        a2 = fmaf(wv2.x, h2[c], a2); a2 = fmaf(wv2.y, h2[c+1], a2); a2 = fmaf(wv2.z, h2[c+2], a2); a2 = fmaf(wv2.w, h2[c+3], a2);
        a3 = fmaf(wv3.x, h2[c], a3); a3 = fmaf(wv3.y, h2[c+1], a3); a3 = fmaf(wv3.z, h2[c+2], a3); a3 = fmaf(wv3.w, h2[c+3], a3);
      }
      float4 ov;
      ov.x = fmaxf(fmaf(a0, S->ss2[o    ], S->ee2[o    ]), 0.0f);
      ov.y = fmaxf(fmaf(a1, S->ss2[o + 1], S->ee2[o + 1]), 0.0f);
      ov.z = fmaxf(fmaf(a2, S->ss2[o + 2], S->ee2[o + 2]), 0.0f);
      ov.w = fmaxf(fmaf(a3, S->ss2[o + 3], S->ee2[o + 3]), 0.0f);
      h3[o] = ov.x; h3[o + 1] = ov.y; h3[o + 2] = ov.z; h3[o + 3] = ov.w;
      *(float4*)(orow + o) = ov;
    }
    // P row = [xyz, h3] @ A   (ascending-c order, identical to round-0)
    const float* pr = pts + r * PTDIM;
    float x0 = pr[0], y0 = pr[1], z0 = pr[2];
    float* prow = P + r * 128;
    for (int grp = 0; grp < 4; grp++) {
      const int g0 = grp * 32;
      float acc[32];
      #pragma unroll
      for (int j = 0; j < 32; j++) {
        float a0 = S->As[0 * 128 + g0 + j];
        float a1 = S->As[1 * 128 + g0 + j];
        float a2 = S->As[2 * 128 + g0 + j];
        acc[j] = fmaf(z0, a2, fmaf(y0, a1, x0 * a0));
      }
      #pragma unroll
      for (int c = 0; c < 128; c++) {
        float s = h3[c];
        const float* arow = &S->As[(3 + c) * 128 + g0];
        #pragma unroll
        for (int j = 0; j < 32; j += 4) {
          float4 a = *(const float4*)&arow[j];
          acc[j]   = fmaf(s, a.x, acc[j]);
          acc[j+1] = fmaf(s, a.y, acc[j+1]);
          acc[j+2] = fmaf(s, a.z, acc[j+2]);
          acc[j+3] = fmaf(s, a.w, acc[j+3]);
        }
      }
      #pragma unroll
      for (int j = 0; j < 32; j += 4)
        *(float4*)(prow + g0 + j) = make_float4(acc[j], acc[j+1], acc[j+2], acc[j+3]);
    }
  }
}

__global__ __launch_bounds__(256) void f1_kernel(const float* __restrict__ pts,
    const float* __restrict__ W0, const float* __restrict__ B0, const float* __restrict__ G0, const float* __restrict__ E0,
    const float* __restrict__ W1, const float* __restrict__ B1, const float* __restrict__ G1, const float* __restrict__ E1,
    const float* __restrict__ W2, const float* __restrict__ B2, const float* __restrict__ G2, const float* __restrict__ E2,
    const float* __restrict__ Aatt,
    float* __restrict__ mfeat, float* __restrict__ P, int* __restrict__ cidx,
    float* __restrict__ X, float* __restrict__ Y, float* __restrict__ Z) {
  __shared__ __align__(16) char smem[F1_SMEM];
  if (blockIdx.x < 8)
    fps_body(smem, pts, cidx, X, Y, Z);
  else
    projmlp_body(smem, pts, W0, B0, G0, E0, W1, B1, G1, E1, W2, B2, G2, E2,
                 Aatt, mfeat, P);
}

// ---------------------------------------------------------------------------
// F2ATTN: fused ball query + attention (round-8 verbatim, measured neutral
// vs split — kept for the single launch boundary). 2048 blocks, 4 waves;
// wave w ball-queries center grp*4+w (exact f2 code; gidx stays in LDS),
// then the block runs attention for its 4 centers (exact attn code).
// Batch-per-XCD swizzle (b = blockIdx&7) covers BOTH phases.
// ---------------------------------------------------------------------------
__global__ __launch_bounds__(256) void f2attn_kernel(
    const float* __restrict__ X, const float* __restrict__ Y, const float* __restrict__ Z,
    const float* __restrict__ mfeat, const float* __restrict__ P,
    const int* __restrict__ cidx, float* __restrict__ out) {
  __shared__ float dbuf[4][512];
  __shared__ int   ibuf[4][512];
  __shared__ int   gidxS[4][32];
  __shared__ int   cIS[4];
  __shared__ float pcS[128];
  const int t = threadIdx.x;
  const int w = t >> 6, lane = t & 63;
  const int b = blockIdx.x & 7;                    // batch-per-XCD swizzle
  const int grp = blockIdx.x >> 3;                 // 0..255
  const int pc = b * NPOINT + grp * 4 + w;         // this wave's center
  const float* Xb = X + b * NPTS;
  const float* Yb = Y + b * NPTS;
  const float* Zb = Z + b * NPTS;
  const float R2 = 0.04f;

  // --- ball query (exact f2 algorithm, per wave) ---
  const int cI = cidx[pc];
  if (lane == 0) cIS[w] = cI;
  const float cx = Xb[cI], cy = Yb[cI], cz = Zb[cI];
  const float sc = __fadd_rn(__fadd_rn(__fmul_rn(cx, cx), __fmul_rn(cy, cy)), __fmul_rn(cz, cz));
  int cnt = 0;                                     // wave-uniform
  for (int rr = 0; rr < 16; rr++) {
    const int base = rr * 256 + lane * 4;
    float4 px4 = *(const float4*)(Xb + base);
    float4 py4 = *(const float4*)(Yb + base);
    float4 pz4 = *(const float4*)(Zb + base);
    #pragma unroll
    for (int e = 0; e < 4; e++) {
      float px = e == 0 ? px4.x : e == 1 ? px4.y : e == 2 ? px4.z : px4.w;
      float py = e == 0 ? py4.x : e == 1 ? py4.y : e == 2 ? py4.z : py4.w;
      float pz = e == 0 ? pz4.x : e == 1 ? pz4.y : e == 2 ? pz4.z : pz4.w;
      float dot = __fadd_rn(__fadd_rn(__fmul_rn(cx, px), __fmul_rn(cy, py)), __fmul_rn(cz, pz));
      float sx  = __fadd_rn(__fadd_rn(__fmul_rn(px, px), __fmul_rn(py, py)), __fmul_rn(pz, pz));
      float d   = __fadd_rn(__fadd_rn(__fmul_rn(-2.0f, dot), sc), sx);
      bool pred = !(d > R2);
      unsigned long long mask = __ballot(pred);
      if (pred) {
        int pos = cnt + (int)__popcll(mask & ((1ull << lane) - 1ull));
        if (pos < 512) { dbuf[w][pos] = d; ibuf[w][pos] = base + e; }
      }
      cnt += (int)__popcll(mask);
    }
  }
  const int K = cnt < 512 ? cnt : 512;
  unsigned long long kk[8];
  #pragma unroll
  for (int kq = 0; kq < 8; kq++) {
    int pos = lane + 64 * kq;
    if (pos < K)
      kk[kq] = ((unsigned long long)fmap(dbuf[w][pos]) << 32) | (unsigned)ibuf[w][pos];
    else
      kk[kq] = ((unsigned long long)FMAP_INF << 32) | 0x7fffffffu;
  }
  int first = 0;
  for (int it = 0; it < NSAMPLE; it++) {
    unsigned long long best = kk[0];
    #pragma unroll
    for (int kq = 1; kq < 8; kq++) if (kk[kq] < best) best = kk[kq];
    unsigned hi = (unsigned)(best >> 32), lo = (unsigned)best;
    dpp_min2<DPP_QUAD_XOR1>(hi, lo);
    dpp_min2<DPP_QUAD_XOR2>(hi, lo);
    dpp_min2<DPP_ROW_HALF_MIRROR>(hi, lo);
    dpp_min2<DPP_ROW_MIRROR>(hi, lo);
    dpp_min2<DPP_ROW_BCAST15>(hi, lo);
    dpp_min2<DPP_ROW_BCAST31>(hi, lo);             // lane63 = wave min
    unsigned blo = (unsigned)__builtin_amdgcn_readlane((int)lo, 63);
    #pragma unroll
    for (int kq = 0; kq < 8; kq++)
      if ((unsigned)kk[kq] == blo)
        kk[kq] = (kk[kq] & 0xFFFFFFFFull) | ((unsigned long long)FMAP_INF << 32);
    if (it == 0) first = (int)blo;
    if (lane == 0) gidxS[w][it] = (it < K) ? (int)blo : first;
  }
  __syncthreads();                                 // gidxS/cIS visible to block

  // --- attention for the block's 4 centers (exact attn algorithm) ---
  for (int cc = 0; cc < 4; cc++) {
    const int pcc = b * NPOINT + grp * 4 + cc;
    const int cIc = cIS[cc];
    if (t < 128) pcS[t] = P[((size_t)b * NPTS + cIc) * 128 + t];
    __syncthreads();
    const int n = t & 31, q = t >> 5;              // q: 0..7, 16 channels each
    const int g = gidxS[cc][n];
    const float* Pg = P + ((size_t)b * NPTS + g) * 128 + q * 16;
    const float* Gf = mfeat + ((size_t)b * NPTS + g) * 128 + q * 16;
    float a[16], gfv[16];
    #pragma unroll
    for (int kq = 0; kq < 4; kq++) {
      float4 vg = *(const float4*)(Pg + 4 * kq);
      float4 vc = *(const float4*)&pcS[q * 16 + 4 * kq];   // LDS broadcast
      float4 vf = *(const float4*)(Gf + 4 * kq);
      a[4*kq]   = vg.x - vc.x; a[4*kq+1] = vg.y - vc.y;
      a[4*kq+2] = vg.z - vc.z; a[4*kq+3] = vg.w - vc.w;
      gfv[4*kq] = vf.x; gfv[4*kq+1] = vf.y; gfv[4*kq+2] = vf.z; gfv[4*kq+3] = vf.w;
    }
    #pragma unroll
    for (int j = 0; j < 16; j++) a[j] = a[j] >= 0.0f ? a[j] : 0.2f * a[j];
    float e[16], s[16], num[16];
    #pragma unroll
    for (int j = 0; j < 16; j++) {
      float mx = red32_max(a[j]);
      e[j] = expf(a[j] - mx);
    }
    #pragma unroll
    for (int j = 0; j < 16; j++) s[j] = red32_sum(e[j]);
    #pragma unroll
    for (int j = 0; j < 16; j++) num[j] = red32_sum(e[j] * gfv[j]);
    if (n == 0) {
      float* orow = out + (size_t)pcc * 131;
      #pragma unroll
      for (int j = 0; j < 16; j++) orow[3 + q * 16 + j] = num[j] / s[j];
      if (q == 0) {
        orow[0] = Xb[cIc]; orow[1] = Yb[cIc]; orow[2] = Zb[cIc];
      }
    }
    __syncthreads();                               // pcS reuse barrier
  }
}

// ---------------------------------------------------------------------------
extern "C" void kernel_launch(void* const* d_in, const int* in_sizes, int n_in,
                              void* d_out, int out_size, void* d_ws, size_t ws_size,
                              hipStream_t stream) {
  const float* points = (const float*)d_in[0];
  const float* W0 = (const float*)d_in[1];
  const float* B0 = (const float*)d_in[2];
  const float* G0 = (const float*)d_in[3];
  const float* E0 = (const float*)d_in[4];
  const float* W1 = (const float*)d_in[5];
  const float* B1 = (const float*)d_in[6];
  const float* G1 = (const float*)d_in[7];
  const float* E1 = (const float*)d_in[8];
  const float* W2 = (const float*)d_in[9];
  const float* B2 = (const float*)d_in[10];
  const float* G2 = (const float*)d_in[11];
  const float* E2 = (const float*)d_in[12];
  const float* Aatt = (const float*)d_in[13];
  float* out = (float*)d_out;

  // workspace (floats): mfeat 4.19M | P 4.19M | X/Y/Z 3*32k | cidx 8k  (~34 MB)
  float* mfeat = (float*)d_ws;
  float* Pw = mfeat + (size_t)NBATCH * NPTS * 128;
  float* Xw = Pw + (size_t)NBATCH * NPTS * 128;
  float* Yw = Xw + NBATCH * NPTS;
  float* Zw = Yw + NBATCH * NPTS;
  int* cidxw = (int*)(Zw + NBATCH * NPTS);

  f1_kernel<<<8 + 64, 256, 0, stream>>>(points,
      W0, B0, G0, E0, W1, B1, G1, E1, W2, B2, G2, E2, Aatt,
      mfeat, Pw, cidxw, Xw, Yw, Zw);
  f2attn_kernel<<<NBATCH * NPOINT / 4, 256, 0, stream>>>(Xw, Yw, Zw,
      mfeat, Pw, cidxw, out);
}

// Round 10
// 791.605 us; speedup vs baseline: 1.7169x; 1.0036x over previous
//
#include <hip/hip_runtime.h>
#include <math.h>

#define NBATCH 8
#define NPTS 4096
#define NPOINT 1024
#define NSAMPLE 32
#define PTDIM 67        // 3 xyz + 64 feat
#define BIGF 1e10f

// DPP ctrl encodings (gfx9/CDNA)
#define DPP_QUAD_XOR1 0xB1   // quad_perm [1,0,3,2]
#define DPP_QUAD_XOR2 0x4E   // quad_perm [2,3,0,1]
#define DPP_ROW_HALF_MIRROR 0x141
#define DPP_ROW_MIRROR 0x140
#define DPP_ROW_BCAST15 0x142
#define DPP_ROW_BCAST31 0x143

template <int CTRL>
__device__ inline float dpp_mov_f(float v) {
  int i = __float_as_int(v);
  return __int_as_float(__builtin_amdgcn_update_dpp(i, i, CTRL, 0xf, 0xf, false));
}
template <int CTRL>
__device__ inline unsigned dpp_mov_u(unsigned v) {
  return (unsigned)__builtin_amdgcn_update_dpp((int)v, (int)v, CTRL, 0xf, 0xf, false);
}
template <int CTRL>
__device__ inline void dpp_min2(unsigned& hi, unsigned& lo) {
  unsigned nh = dpp_mov_u<CTRL>(hi);
  unsigned nl = dpp_mov_u<CTRL>(lo);
  bool take = (nh < hi) || (nh == hi && nl < lo);
  hi = take ? nh : hi;
  lo = take ? nl : lo;
}
// Pair-key MAX step for FPS argmax: key = (hi=dbits, lo=4095-j), u64 compare.
// Proved -43us on the FPS serial chain in round 9 (650 -> 607 us).
template <int CTRL>
__device__ inline void dpp_max2(unsigned& hi, unsigned& lo) {
  unsigned nh = dpp_mov_u<CTRL>(hi);
  unsigned nl = dpp_mov_u<CTRL>(lo);
  unsigned long long k0 = ((unsigned long long)hi << 32) | lo;
  unsigned long long k1 = ((unsigned long long)nh << 32) | nl;
  bool take = k1 > k0;
  hi = take ? nh : hi;
  lo = take ? nl : lo;
}
__device__ inline unsigned fmap(float d) {
  unsigned b = __float_as_uint(d);
  return ((int)b < 0) ? ~b : (b | 0x80000000u);
}
#define FMAP_INF 0xFF800000u   // fmap(+INF)

// 32-lane-group reductions: 4 VALU-DPP levels + ONE shfl (xor16) per value.
__device__ inline float red32_max(float v) {
  v = fmaxf(v, dpp_mov_f<DPP_QUAD_XOR1>(v));
  v = fmaxf(v, dpp_mov_f<DPP_QUAD_XOR2>(v));
  v = fmaxf(v, dpp_mov_f<DPP_ROW_HALF_MIRROR>(v));
  v = fmaxf(v, dpp_mov_f<DPP_ROW_MIRROR>(v));
  v = fmaxf(v, __shfl_xor(v, 16));
  return v;
}
__device__ inline float red32_sum(float v) {
  v += dpp_mov_f<DPP_QUAD_XOR1>(v);
  v += dpp_mov_f<DPP_QUAD_XOR2>(v);
  v += dpp_mov_f<DPP_ROW_HALF_MIRROR>(v);
  v += dpp_mov_f<DPP_ROW_MIRROR>(v);
  v += __shfl_xor(v, 16);
  return v;
}

// ---------------------------------------------------------------------------
// F1: fused FPS (blocks 0..7; also emits SoA xyz) + PROJ-MLP (blocks 8..71).
// ROUND-9 VERBATIM (measured 607 us): single pair-key DPP argmax chain.
// ---------------------------------------------------------------------------
struct FpsS {
  unsigned long long slots[2][4];
  int cidxS[NPOINT];
  float4 C[NPTS];
};
struct ProjS {
  float As[131 * 128];                             // a_att row-major
  float w0[64 * 64], w1[64 * 64], w2[128 * 64];
  float bb0[64], ss0[64], ee0[64];
  float bb1[64], ss1[64], ee1[64];
  float bb2[128], ss2[128], ee2[128];
};
#define F1_SMEM (sizeof(ProjS) > sizeof(FpsS) ? sizeof(ProjS) : sizeof(FpsS))

// FPS: one block per batch, 256 thr, 16 pts/lane, pk-f32 dist update under
// contract(off) (IEEE-identical per component). Exact f32 replication of
// jnp: ((dx*dx+dy*dy)+dz*dz), min, argmax first-idx.
__device__ void fps_body(char* smemRaw, const float* __restrict__ pts,
                         int* __restrict__ cidx, float* __restrict__ X,
                         float* __restrict__ Y, float* __restrict__ Z) {
#pragma clang fp contract(off)
  FpsS* S = (FpsS*)smemRaw;
  const int b = blockIdx.x, tid = threadIdx.x;
  const int w = tid >> 6, lane = tid & 63;
  const float* pb = pts + (size_t)b * NPTS * PTDIM;
  float2 px2[8], py2[8], pz2[8];
  float dl[16];
  #pragma unroll
  for (int k = 0; k < 16; k++) {
    int j = tid + (k << 8);
    const float* pj = pb + (size_t)j * PTDIM;
    float x = pj[0], y = pj[1], z = pj[2];
    if (k & 1) { px2[k >> 1].y = x; py2[k >> 1].y = y; pz2[k >> 1].y = z; }
    else       { px2[k >> 1].x = x; py2[k >> 1].x = y; pz2[k >> 1].x = z; }
    S->C[j] = make_float4(x, y, z, 0.0f);
    X[b * NPTS + j] = x; Y[b * NPTS + j] = y; Z[b * NPTS + j] = z;  // SoA out
    dl[k] = BIGF;
  }
  __syncthreads();
  const unsigned jb = 4095u - (unsigned)tid;       // jp(k) = jb - (k<<8)
  int f = 0;
  float4 c0 = S->C[0];
  float cx = c0.x, cy = c0.y, cz = c0.z;
  for (int t = 0; t < NPOINT; t++) {
    if (tid == 0) S->cidxS[t] = f;                 // emit BEFORE update
    float2 c2x = make_float2(cx, cx);
    float2 c2y = make_float2(cy, cy);
    float2 c2z = make_float2(cz, cz);
    #pragma unroll
    for (int m = 0; m < 8; m++) {
      float2 dx = px2[m] - c2x;
      float2 dy = py2[m] - c2y;
      float2 dz = pz2[m] - c2z;
      float2 d = (dx * dx + dy * dy) + dz * dz;    // pk ops, contract OFF
      dl[2 * m]     = fminf(dl[2 * m],     d.x);
      dl[2 * m + 1] = fminf(dl[2 * m + 1], d.y);
    }
    // Local 16 -> 1 argmax carrying (d, jp=4095-j). Strict '>' keeps LEFT on
    // ties == first index (j ascends with k). 3 instr per merge.
    float td[8]; unsigned tj[8];
    #pragma unroll
    for (int m = 0; m < 8; m++) {
      bool take = dl[2 * m + 1] > dl[2 * m];
      td[m] = take ? dl[2 * m + 1] : dl[2 * m];
      tj[m] = jb - (unsigned)((take ? (2 * m + 1) : (2 * m)) << 8);
    }
    #pragma unroll
    for (int m = 0; m < 4; m++) {
      bool take = td[2 * m + 1] > td[2 * m];
      td[m] = take ? td[2 * m + 1] : td[2 * m];
      tj[m] = take ? tj[2 * m + 1] : tj[2 * m];
    }
    #pragma unroll
    for (int m = 0; m < 2; m++) {
      bool take = td[2 * m + 1] > td[2 * m];
      td[m] = take ? td[2 * m + 1] : td[2 * m];
      tj[m] = take ? tj[2 * m + 1] : tj[2 * m];
    }
    {
      bool take = td[1] > td[0];
      td[0] = take ? td[1] : td[0];
      tj[0] = take ? tj[1] : tj[0];
    }
    // Wave 64 -> 1: single pair-key DPP chain. d >= 0 so float bits are
    // unsigned-monotone; jp in the low word resolves ties to min j exactly.
    unsigned hi = __float_as_uint(td[0]), lo = tj[0];
    dpp_max2<DPP_QUAD_XOR1>(hi, lo);
    dpp_max2<DPP_QUAD_XOR2>(hi, lo);
    dpp_max2<DPP_ROW_HALF_MIRROR>(hi, lo);
    dpp_max2<DPP_ROW_MIRROR>(hi, lo);
    dpp_max2<DPP_ROW_BCAST15>(hi, lo);
    dpp_max2<DPP_ROW_BCAST31>(hi, lo);             // lane63 = wave winner
    if (lane == 63)
      S->slots[t & 1][w] = ((unsigned long long)hi << 32) |
                           (unsigned long long)lo;  // same encoding as before
    __syncthreads();
    unsigned long long s0 = S->slots[t & 1][0], s1 = S->slots[t & 1][1];
    unsigned long long s2 = S->slots[t & 1][2], s3 = S->slots[t & 1][3];
    unsigned long long m0 = s0 > s1 ? s0 : s1;
    unsigned long long m1 = s2 > s3 ? s2 : s3;
    unsigned long long best = m0 > m1 ? m0 : m1;
    f = NPTS - 1 - (int)(best & 0xFFFFFFFFull);
    float4 cc = S->C[f];
    cx = cc.x; cy = cc.y; cz = cc.z;
  }
  __syncthreads();
  for (int i = tid; i < NPOINT; i += 256) cidx[b * NPOINT + i] = S->cidxS[i];
}

// PROJ-MLP: 64 blocks x 512 rows (2 rows/thread, sequential). Round-0
// verbatim: all weights + A staged in LDS; op order bit-identical.
__device__ void projmlp_body(char* smemRaw, const float* __restrict__ pts,
    const float* __restrict__ W0, const float* __restrict__ B0, const float* __restrict__ G0, const float* __restrict__ E0,
    const float* __restrict__ W1, const float* __restrict__ B1, const float* __restrict__ G1, const float* __restrict__ E1,
    const float* __restrict__ W2, const float* __restrict__ B2, const float* __restrict__ G2, const float* __restrict__ E2,
    const float* __restrict__ Aatt,
    float* __restrict__ mfeat, float* __restrict__ P) {
  ProjS* S = (ProjS*)smemRaw;
  const float INVS = 0.99999500003750f;            // 1/sqrt(1+1e-5)
  const int t = threadIdx.x;
  for (int i = t; i < 131 * 128; i += 256) S->As[i] = Aatt[i];
  for (int i = t; i < 4096; i += 256) { S->w0[i] = W0[i]; S->w1[i] = W1[i]; }
  for (int i = t; i < 8192; i += 256) S->w2[i] = W2[i];
  if (t < 64) {
    S->bb0[t] = B0[t]; S->ss0[t] = G0[t] * INVS; S->ee0[t] = E0[t];
    S->bb1[t] = B1[t]; S->ss1[t] = G1[t] * INVS; S->ee1[t] = E1[t];
  }
  if (t < 128) { S->bb2[t] = B2[t]; S->ss2[t] = G2[t] * INVS; S->ee2[t] = E2[t]; }
  __syncthreads();

  const int pb = blockIdx.x - 8;                   // 0..63
  for (int rr = 0; rr < 2; rr++) {
    const size_t r = (size_t)pb * 512 + rr * 256 + t;   // row 0..32767
    const float* xr = pts + r * PTDIM + 3;
    float x[64];
    #pragma unroll
    for (int c = 0; c < 64; c++) x[c] = xr[c];

    float h1[64];
    #pragma unroll
    for (int o = 0; o < 64; o++) {
      float acc = S->bb0[o];
      #pragma unroll
      for (int c = 0; c < 64; c += 4) {
        float4 wv = *(const float4*)&S->w0[o * 64 + c];
        acc = fmaf(wv.x, x[c], acc);
        acc = fmaf(wv.y, x[c + 1], acc);
        acc = fmaf(wv.z, x[c + 2], acc);
        acc = fmaf(wv.w, x[c + 3], acc);
      }
      h1[o] = fmaxf(fmaf(acc, S->ss0[o], S->ee0[o]), 0.0f);
    }
    float h2[64];
    #pragma unroll
    for (int o = 0; o < 64; o++) {
      float acc = S->bb1[o];
      #pragma unroll
      for (int c = 0; c < 64; c += 4) {
        float4 wv = *(const float4*)&S->w1[o * 64 + c];
        acc = fmaf(wv.x, h1[c], acc);
        acc = fmaf(wv.y, h1[c + 1], acc);
        acc = fmaf(wv.z, h1[c + 2], acc);
        acc = fmaf(wv.w, h1[c + 3], acc);
      }
      h2[o] = fmaxf(fmaf(acc, S->ss1[o], S->ee1[o]), 0.0f);
    }
    float h3[128];
    float* orow = mfeat + r * 128;
    #pragma unroll
    for (int o = 0; o < 128; o += 4) {
      float a0 = S->bb2[o], a1 = S->bb2[o + 1], a2 = S->bb2[o + 2], a3 = S->bb2[o + 3];
      #pragma unroll
      for (int c = 0; c < 64; c += 4) {
        float4 wv0 = *(const float4*)&S->w2[(o    ) * 64 + c];
        float4 wv1 = *(const float4*)&S->w2[(o + 1) * 64 + c];
        float4 wv2 = *(const float4*)&S->w2[(o + 2) * 64 + c];
        float4 wv3 = *(const float4*)&S->w2[(o + 3) * 64 + c];
        a0 = fmaf(wv0.x, h2[c], a0); a0 = fmaf(wv0.y, h2[c+1], a0); a0 = fmaf(wv0.z, h2[c+2], a0); a0 = fmaf(wv0.w, h2[c+3], a0);
        a1 = fmaf(wv1.x, h2[c], a1); a1 = fmaf(wv1.y, h2[c+1], a1); a1 = fmaf(wv1.z, h2[c+2], a1); a1 = fmaf(wv1.w, h2[c+3], a1);
        a2 = fmaf(wv2.x, h2[c], a2); a2 = fmaf(wv2.y, h2[c+1], a2); a2 = fmaf(wv2.z, h2[c+2], a2); a2 = fmaf(wv2.w, h2[c+3], a2);
        a3 = fmaf(wv3.x, h2[c], a3); a3 = fmaf(wv3.y, h2[c+1], a3); a3 = fmaf(wv3.z, h2[c+2], a3); a3 = fmaf(wv3.w, h2[c+3], a3);
      }
      float4 ov;
      ov.x = fmaxf(fmaf(a0, S->ss2[o    ], S->ee2[o    ]), 0.0f);
      ov.y = fmaxf(fmaf(a1, S->ss2[o + 1], S->ee2[o + 1]), 0.0f);
      ov.z = fmaxf(fmaf(a2, S->ss2[o + 2], S->ee2[o + 2]), 0.0f);
      ov.w = fmaxf(fmaf(a3, S->ss2[o + 3], S->ee2[o + 3]), 0.0f);
      h3[o] = ov.x; h3[o + 1] = ov.y; h3[o + 2] = ov.z; h3[o + 3] = ov.w;
      *(float4*)(orow + o) = ov;
    }
    // P row = [xyz, h3] @ A   (ascending-c order, identical to round-0)
    const float* pr = pts + r * PTDIM;
    float x0 = pr[0], y0 = pr[1], z0 = pr[2];
    float* prow = P + r * 128;
    for (int grp = 0; grp < 4; grp++) {
      const int g0 = grp * 32;
      float acc[32];
      #pragma unroll
      for (int j = 0; j < 32; j++) {
        float a0 = S->As[0 * 128 + g0 + j];
        float a1 = S->As[1 * 128 + g0 + j];
        float a2 = S->As[2 * 128 + g0 + j];
        acc[j] = fmaf(z0, a2, fmaf(y0, a1, x0 * a0));
      }
      #pragma unroll
      for (int c = 0; c < 128; c++) {
        float s = h3[c];
        const float* arow = &S->As[(3 + c) * 128 + g0];
        #pragma unroll
        for (int j = 0; j < 32; j += 4) {
          float4 a = *(const float4*)&arow[j];
          acc[j]   = fmaf(s, a.x, acc[j]);
          acc[j+1] = fmaf(s, a.y, acc[j+1]);
          acc[j+2] = fmaf(s, a.z, acc[j+2]);
          acc[j+3] = fmaf(s, a.w, acc[j+3]);
        }
      }
      #pragma unroll
      for (int j = 0; j < 32; j += 4)
        *(float4*)(prow + g0 + j) = make_float4(acc[j], acc[j+1], acc[j+2], acc[j+3]);
    }
  }
}

__global__ __launch_bounds__(256) void f1_kernel(const float* __restrict__ pts,
    const float* __restrict__ W0, const float* __restrict__ B0, const float* __restrict__ G0, const float* __restrict__ E0,
    const float* __restrict__ W1, const float* __restrict__ B1, const float* __restrict__ G1, const float* __restrict__ E1,
    const float* __restrict__ W2, const float* __restrict__ B2, const float* __restrict__ G2, const float* __restrict__ E2,
    const float* __restrict__ Aatt,
    float* __restrict__ mfeat, float* __restrict__ P, int* __restrict__ cidx,
    float* __restrict__ X, float* __restrict__ Y, float* __restrict__ Z) {
  __shared__ __align__(16) char smem[F1_SMEM];
  if (blockIdx.x < 8)
    fps_body(smem, pts, cidx, X, Y, Z);
  else
    projmlp_body(smem, pts, W0, B0, G0, E0, W1, B1, G1, E1, W2, B2, G2, E2,
                 Aatt, mfeat, P);
}

// ---------------------------------------------------------------------------
// F2ATTN: fused ball query + attention. 2048 blocks, 4 waves; wave w
// ball-queries center grp*4+w (exact f2 code; gidx stays in LDS). ATTENTION
// PHASE RESTRUCTURED: all 4 centers' P rows staged into pcS4[4][128] behind
// ONE barrier, then the 4-cc loop runs UNROLLED WITH ZERO BARRIERS — the
// compiler can hoist cc_{k+1}'s independent P/mfeat gathers above cc_k's
// DPP reductions, hiding L2 gather latency under compute (previously 2
// barriers/cc serialized every gather round). Per-channel arithmetic order
// unchanged -> bit-identical output.
// ---------------------------------------------------------------------------
__global__ __launch_bounds__(256) void f2attn_kernel(
    const float* __restrict__ X, const float* __restrict__ Y, const float* __restrict__ Z,
    const float* __restrict__ mfeat, const float* __restrict__ P,
    const int* __restrict__ cidx, float* __restrict__ out) {
  __shared__ float dbuf[4][512];
  __shared__ int   ibuf[4][512];
  __shared__ int   gidxS[4][32];
  __shared__ int   cIS[4];
  __shared__ float pcS4[4][128];
  const int t = threadIdx.x;
  const int w = t >> 6, lane = t & 63;
  const int b = blockIdx.x & 7;                    // batch-per-XCD swizzle
  const int grp = blockIdx.x >> 3;                 // 0..255
  const int pc = b * NPOINT + grp * 4 + w;         // this wave's center
  const float* Xb = X + b * NPTS;
  const float* Yb = Y + b * NPTS;
  const float* Zb = Z + b * NPTS;
  const float R2 = 0.04f;

  // --- ball query (exact f2 algorithm, per wave) ---
  const int cI = cidx[pc];
  if (lane == 0) cIS[w] = cI;
  const float cx = Xb[cI], cy = Yb[cI], cz = Zb[cI];
  const float sc = __fadd_rn(__fadd_rn(__fmul_rn(cx, cx), __fmul_rn(cy, cy)), __fmul_rn(cz, cz));
  int cnt = 0;                                     // wave-uniform
  for (int rr = 0; rr < 16; rr++) {
    const int base = rr * 256 + lane * 4;
    float4 px4 = *(const float4*)(Xb + base);
    float4 py4 = *(const float4*)(Yb + base);
    float4 pz4 = *(const float4*)(Zb + base);
    #pragma unroll
    for (int e = 0; e < 4; e++) {
      float px = e == 0 ? px4.x : e == 1 ? px4.y : e == 2 ? px4.z : px4.w;
      float py = e == 0 ? py4.x : e == 1 ? py4.y : e == 2 ? py4.z : py4.w;
      float pz = e == 0 ? pz4.x : e == 1 ? pz4.y : e == 2 ? pz4.z : pz4.w;
      float dot = __fadd_rn(__fadd_rn(__fmul_rn(cx, px), __fmul_rn(cy, py)), __fmul_rn(cz, pz));
      float sx  = __fadd_rn(__fadd_rn(__fmul_rn(px, px), __fmul_rn(py, py)), __fmul_rn(pz, pz));
      float d   = __fadd_rn(__fadd_rn(__fmul_rn(-2.0f, dot), sc), sx);
      bool pred = !(d > R2);
      unsigned long long mask = __ballot(pred);
      if (pred) {
        int pos = cnt + (int)__popcll(mask & ((1ull << lane) - 1ull));
        if (pos < 512) { dbuf[w][pos] = d; ibuf[w][pos] = base + e; }
      }
      cnt += (int)__popcll(mask);
    }
  }
  const int K = cnt < 512 ? cnt : 512;
  unsigned long long kk[8];
  #pragma unroll
  for (int kq = 0; kq < 8; kq++) {
    int pos = lane + 64 * kq;
    if (pos < K)
      kk[kq] = ((unsigned long long)fmap(dbuf[w][pos]) << 32) | (unsigned)ibuf[w][pos];
    else
      kk[kq] = ((unsigned long long)FMAP_INF << 32) | 0x7fffffffu;
  }
  int first = 0;
  for (int it = 0; it < NSAMPLE; it++) {
    unsigned long long best = kk[0];
    #pragma unroll
    for (int kq = 1; kq < 8; kq++) if (kk[kq] < best) best = kk[kq];
    unsigned hi = (unsigned)(best >> 32), lo = (unsigned)best;
    dpp_min2<DPP_QUAD_XOR1>(hi, lo);
    dpp_min2<DPP_QUAD_XOR2>(hi, lo);
    dpp_min2<DPP_ROW_HALF_MIRROR>(hi, lo);
    dpp_min2<DPP_ROW_MIRROR>(hi, lo);
    dpp_min2<DPP_ROW_BCAST15>(hi, lo);
    dpp_min2<DPP_ROW_BCAST31>(hi, lo);             // lane63 = wave min
    unsigned blo = (unsigned)__builtin_amdgcn_readlane((int)lo, 63);
    #pragma unroll
    for (int kq = 0; kq < 8; kq++)
      if ((unsigned)kk[kq] == blo)
        kk[kq] = (kk[kq] & 0xFFFFFFFFull) | ((unsigned long long)FMAP_INF << 32);
    if (it == 0) first = (int)blo;
    if (lane == 0) gidxS[w][it] = (it < K) ? (int)blo : first;
  }
  __syncthreads();                                 // gidxS/cIS visible to block

  // --- stage all 4 centers' P rows (one pass, one barrier) ---
  #pragma unroll
  for (int s = t; s < 512; s += 256) {
    const int scc = s >> 7, se = s & 127;
    pcS4[scc][se] = P[((size_t)b * NPTS + cIS[scc]) * 128 + se];
  }
  __syncthreads();

  // --- attention for the block's 4 centers: UNROLLED, NO BARRIERS ---
  const int n = t & 31, q = t >> 5;                // q: 0..7, 16 channels each
  #pragma unroll
  for (int cc = 0; cc < 4; cc++) {
    const int pcc = b * NPOINT + grp * 4 + cc;
    const int cIc = cIS[cc];
    const int g = gidxS[cc][n];
    const float* Pg = P + ((size_t)b * NPTS + g) * 128 + q * 16;
    const float* Gf = mfeat + ((size_t)b * NPTS + g) * 128 + q * 16;
    float a[16], gfv[16];
    #pragma unroll
    for (int kq = 0; kq < 4; kq++) {
      float4 vg = *(const float4*)(Pg + 4 * kq);
      float4 vc = *(const float4*)&pcS4[cc][q * 16 + 4 * kq];   // LDS broadcast
      float4 vf = *(const float4*)(Gf + 4 * kq);
      a[4*kq]   = vg.x - vc.x; a[4*kq+1] = vg.y - vc.y;
      a[4*kq+2] = vg.z - vc.z; a[4*kq+3] = vg.w - vc.w;
      gfv[4*kq] = vf.x; gfv[4*kq+1] = vf.y; gfv[4*kq+2] = vf.z; gfv[4*kq+3] = vf.w;
    }
    #pragma unroll
    for (int j = 0; j < 16; j++) a[j] = a[j] >= 0.0f ? a[j] : 0.2f * a[j];
    float e[16], s[16], num[16];
    #pragma unroll
    for (int j = 0; j < 16; j++) {
      float mx = red32_max(a[j]);
      e[j] = expf(a[j] - mx);
    }
    #pragma unroll
    for (int j = 0; j < 16; j++) s[j] = red32_sum(e[j]);
    #pragma unroll
    for (int j = 0; j < 16; j++) num[j] = red32_sum(e[j] * gfv[j]);
    if (n == 0) {
      float* orow = out + (size_t)pcc * 131;
      #pragma unroll
      for (int j = 0; j < 16; j++) orow[3 + q * 16 + j] = num[j] / s[j];
      if (q == 0) {
        orow[0] = Xb[cIc]; orow[1] = Yb[cIc]; orow[2] = Zb[cIc];
      }
    }
  }
}

// ---------------------------------------------------------------------------
extern "C" void kernel_launch(void* const* d_in, const int* in_sizes, int n_in,
                              void* d_out, int out_size, void* d_ws, size_t ws_size,
                              hipStream_t stream) {
  const float* points = (const float*)d_in[0];
  const float* W0 = (const float*)d_in[1];
  const float* B0 = (const float*)d_in[2];
  const float* G0 = (const float*)d_in[3];
  const float* E0 = (const float*)d_in[4];
  const float* W1 = (const float*)d_in[5];
  const float* B1 = (const float*)d_in[6];
  const float* G1 = (const float*)d_in[7];
  const float* E1 = (const float*)d_in[8];
  const float* W2 = (const float*)d_in[9];
  const float* B2 = (const float*)d_in[10];
  const float* G2 = (const float*)d_in[11];
  const float* E2 = (const float*)d_in[12];
  const float* Aatt = (const float*)d_in[13];
  float* out = (float*)d_out;

  // workspace (floats): mfeat 4.19M | P 4.19M | X/Y/Z 3*32k | cidx 8k  (~34 MB)
  float* mfeat = (float*)d_ws;
  float* Pw = mfeat + (size_t)NBATCH * NPTS * 128;
  float* Xw = Pw + (size_t)NBATCH * NPTS * 128;
  float* Yw = Xw + NBATCH * NPTS;
  float* Zw = Yw + NBATCH * NPTS;
  int* cidxw = (int*)(Zw + NBATCH * NPTS);

  f1_kernel<<<8 + 64, 256, 0, stream>>>(points,
      W0, B0, G0, E0, W1, B1, G1, E1, W2, B2, G2, E2, Aatt,
      mfeat, Pw, cidxw, Xw, Yw, Zw);
  f2attn_kernel<<<NBATCH * NPOINT / 4, 256, 0, stream>>>(Xw, Yw, Zw,
      mfeat, Pw, cidxw, out);
}